// Round 7
// baseline (464.151 us; speedup 1.0000x reference)
//
#include <hip/hip_runtime.h>

#define N_NODESC 50000
#define N_EDGESC 800000
#define DIMC 128
#define NGC 64
#define HDC 32
#define SLOPEF 0.01f
#define EPSF 1e-5f
#define SCALEF 0.17677669529663687f  // 32^-0.5

#define NBUK 782   // ceil(50000/64) buckets of 64 dst nodes
#define KBLK 50    // binning blocks
#define EPB 16000  // edges per binning block (50*16000 = 800000)

typedef __attribute__((ext_vector_type(8))) short bf16x8;
typedef __attribute__((ext_vector_type(4))) float f32x4;

// fp32 <-> bf16 (RNE)
static __device__ __forceinline__ unsigned short f2bf(float f) {
  unsigned u = __float_as_uint(f);
  u = u + 0x7FFFu + ((u >> 16) & 1u);
  return (unsigned short)(u >> 16);
}
static __device__ __forceinline__ float bf2f(unsigned short h) {
  return __uint_as_float(((unsigned)h) << 16);
}

// ---------------- CSR build: locality-preserving two-level counting sort ----------------
__global__ __launch_bounds__(1024) void kbhist(const int* __restrict__ ei, int* __restrict__ hist) {
  __shared__ int lh[NBUK];
  int t = threadIdx.x;
  for (int i = t; i < NBUK; i += 1024) lh[i] = 0;
  __syncthreads();
  int e0 = blockIdx.x * EPB;
  for (int e = e0 + t; e < e0 + EPB; e += 1024) {
    int d = ei[N_EDGESC + e];
    atomicAdd(&lh[d >> 6], 1);
  }
  __syncthreads();
  for (int i = t; i < NBUK; i += 1024) hist[blockIdx.x * NBUK + i] = lh[i];
}

__global__ __launch_bounds__(1024) void kbscan(const int* __restrict__ hist, int* __restrict__ bbase,
                                               int* __restrict__ bucket_base) {
  __shared__ int sd[1024];
  int t = threadIdx.x;
  int tot = 0;
  if (t < NBUK) {
    for (int k = 0; k < KBLK; ++k) tot += hist[k * NBUK + t];
  }
  sd[t] = tot;
  __syncthreads();
  for (int off = 1; off < 1024; off <<= 1) {
    int u = (t >= off) ? sd[t - off] : 0;
    __syncthreads();
    sd[t] += u;
    __syncthreads();
  }
  if (t < NBUK) {
    int run = sd[t] - tot;  // exclusive bucket base
    bucket_base[t] = run;
    for (int k = 0; k < KBLK; ++k) {
      bbase[k * NBUK + t] = run;
      run += hist[k * NBUK + t];
    }
  }
  if (t == 0) bucket_base[NBUK] = N_EDGESC;
}

__global__ __launch_bounds__(1024) void kbin(const int* __restrict__ ei, const int* __restrict__ bbase,
                                             unsigned* __restrict__ packed) {
  __shared__ int cur[NBUK];
  int t = threadIdx.x;
  for (int i = t; i < NBUK; i += 1024) cur[i] = bbase[blockIdx.x * NBUK + i];
  __syncthreads();
  int e0 = blockIdx.x * EPB;
  for (int e = e0 + t; e < e0 + EPB; e += 1024) {
    int s = ei[e];
    int d = ei[N_EDGESC + e];
    int b = d >> 6;
    int pos = atomicAdd(&cur[b], 1);
    packed[pos] = (unsigned)s | ((unsigned)(d & 63) << 16);
  }
}

__global__ __launch_bounds__(256) void kcsr(const unsigned* __restrict__ packed, const int* __restrict__ bucket_base,
                                            unsigned short* __restrict__ csr16, int* __restrict__ rowptr,
                                            float* __restrict__ inv) {
  __shared__ int h64[64], o64[64], c64[64];
  int b = blockIdx.x, t = threadIdx.x;
  int beg = bucket_base[b], end = bucket_base[b + 1];
  if (t < 64) h64[t] = 0;
  __syncthreads();
  for (int e = beg + t; e < end; e += 256) atomicAdd(&h64[packed[e] >> 16], 1);
  __syncthreads();
  if (t == 0) {
    int run = 0;
    for (int j = 0; j < 64; ++j) { o64[j] = run; run += h64[j]; }
  }
  __syncthreads();
  if (t < 64) c64[t] = o64[t];
  __syncthreads();
  for (int e = beg + t; e < end; e += 256) {
    unsigned p = packed[e];
    int pos = atomicAdd(&c64[p >> 16], 1);
    csr16[beg + pos] = (unsigned short)(p & 0xFFFFu);
  }
  if (t < 64) {
    int node = b * 64 + t;
    if (node < N_NODESC) {
      rowptr[node] = beg + o64[t];
      inv[node] = rsqrtf((float)h64[t] + 1.0f);
    }
  }
  if (b == NBUK - 1 && t == 0) rowptr[N_NODESC] = N_EDGESC;
}

// ---------------- W pre-transpose: W[k][n] fp32 -> Wt hi/lo bf16 [n][k] ----------------
// Wt layout per matrix: [2][128][128] u16 (hi plane then lo plane). 4 matrices.
__global__ __launch_bounds__(256) void wconv(const float* __restrict__ W0, const float* __restrict__ W1,
                                             const float* __restrict__ W2, const float* __restrict__ W3,
                                             unsigned short* __restrict__ Wt) {
  const float* W = (blockIdx.x == 0) ? W0 : (blockIdx.x == 1) ? W1 : (blockIdx.x == 2) ? W2 : W3;
  unsigned short* hi = Wt + (size_t)blockIdx.x * 2 * DIMC * DIMC;
  unsigned short* lo = hi + DIMC * DIMC;
  int t = threadIdx.x;
  for (int i = t; i < (DIMC / 2) * DIMC; i += 256) {
    int kp = i >> 7, n = i & 127;
    float a = W[(2 * kp) * DIMC + n];
    float b = W[(2 * kp + 1) * DIMC + n];
    unsigned short ah = f2bf(a), bh = f2bf(b);
    unsigned short al = f2bf(a - bf2f(ah)), bl = f2bf(b - bf2f(bh));
    *(unsigned*)&hi[n * DIMC + 2 * kp] = (unsigned)ah | ((unsigned)bh << 16);
    *(unsigned*)&lo[n * DIMC + 2 * kp] = (unsigned)al | ((unsigned)bl << 16);
  }
}

// ---------------- encoder GEMM via MFMA: Y(bf16) = (X @ W) * inv[row] ----------------
// No LDS. 4 waves/block, each wave: 16 rows x 128 cols. A from X (fp32->bf16 in reg),
// B frags from Wt (hi+lo bf16 split -> W-quant error ~2^-16). mfma_f32_16x16x32_bf16:
// A: row=lane&15, k=8*(lane>>4)+j ; B: col=lane&15, same k ; D: col=lane&15, row=4*(lane>>4)+r.
__global__ __launch_bounds__(256) void gemm_mfma(const float* __restrict__ X, const unsigned short* __restrict__ Wt,
                                                 const float* __restrict__ inv, unsigned short* __restrict__ Y) {
  const unsigned short* Whi = Wt;
  const unsigned short* Wlo = Wt + DIMC * DIMC;
  int wave = threadIdx.x >> 6, lane = threadIdx.x & 63;
  int l15 = lane & 15, kb = lane >> 4;
  int row0 = blockIdx.x * 64 + wave * 16;
  int rA = row0 + l15;
  const bool valid = rA < N_NODESC;
  f32x4 acc[8];
#pragma unroll
  for (int nf = 0; nf < 8; ++nf) acc[nf] = 0.f;
#pragma unroll
  for (int ks = 0; ks < 4; ++ks) {
    int kbase = ks * 32 + kb * 8;
    bf16x8 a;
    if (valid) {
      const float* xp = &X[(size_t)rA * DIMC + kbase];
      float4 x0 = *(const float4*)xp;
      float4 x1 = *(const float4*)(xp + 4);
      a[0] = (short)f2bf(x0.x); a[1] = (short)f2bf(x0.y);
      a[2] = (short)f2bf(x0.z); a[3] = (short)f2bf(x0.w);
      a[4] = (short)f2bf(x1.x); a[5] = (short)f2bf(x1.y);
      a[6] = (short)f2bf(x1.z); a[7] = (short)f2bf(x1.w);
    } else {
      a = (short)0;
    }
#pragma unroll
    for (int nf = 0; nf < 8; ++nf) {
      bf16x8 bh = *(const bf16x8*)&Whi[(nf * 16 + l15) * DIMC + kbase];
      bf16x8 bl = *(const bf16x8*)&Wlo[(nf * 16 + l15) * DIMC + kbase];
      acc[nf] = __builtin_amdgcn_mfma_f32_16x16x32_bf16(a, bh, acc[nf], 0, 0, 0);
      acc[nf] = __builtin_amdgcn_mfma_f32_16x16x32_bf16(a, bl, acc[nf], 0, 0, 0);
    }
  }
  int orow = row0 + kb * 4;
#pragma unroll
  for (int r = 0; r < 4; ++r) {
    int rr = orow + r;
    if (rr < N_NODESC) {
      float s = inv[rr];
#pragma unroll
      for (int nf = 0; nf < 8; ++nf) {
        Y[(size_t)rr * DIMC + nf * 16 + l15] = f2bf(acc[nf][r] * s);
      }
    }
  }
}

// ---------------- aggregation: out = (sum_{src} Hs[src] + Hs[i]) * inv[i] + b ----------------
__global__ __launch_bounds__(256) void agg_kernel(const unsigned short* __restrict__ Hs, const float* __restrict__ inv,
                                                  const int* __restrict__ rowptr, const unsigned short* __restrict__ csr,
                                                  const float* __restrict__ bias, float* __restrict__ out,
                                                  int do_relu) {
  int node = blockIdx.x * 4 + (threadIdx.x >> 6);
  if (node >= N_NODESC) return;
  int lane = threadIdx.x & 63;
  int cg = (lane & 31) * 4;
  int slot = lane >> 5;
  int beg = rowptr[node], end = rowptr[node + 1];
  float4 acc = make_float4(0.f, 0.f, 0.f, 0.f);
  int e = beg;
  for (; e + 8 <= end; e += 8) {
    int s0 = csr[e + slot];
    int s1 = csr[e + 2 + slot];
    int s2 = csr[e + 4 + slot];
    int s3 = csr[e + 6 + slot];
    ushort4 v0 = *(const ushort4*)&Hs[(size_t)s0 * DIMC + cg];
    ushort4 v1 = *(const ushort4*)&Hs[(size_t)s1 * DIMC + cg];
    ushort4 v2 = *(const ushort4*)&Hs[(size_t)s2 * DIMC + cg];
    ushort4 v3 = *(const ushort4*)&Hs[(size_t)s3 * DIMC + cg];
    acc.x += (bf2f(v0.x) + bf2f(v1.x)) + (bf2f(v2.x) + bf2f(v3.x));
    acc.y += (bf2f(v0.y) + bf2f(v1.y)) + (bf2f(v2.y) + bf2f(v3.y));
    acc.z += (bf2f(v0.z) + bf2f(v1.z)) + (bf2f(v2.z) + bf2f(v3.z));
    acc.w += (bf2f(v0.w) + bf2f(v1.w)) + (bf2f(v2.w) + bf2f(v3.w));
  }
  for (int t = e + slot; t < end; t += 2) {
    int s = csr[t];
    ushort4 v = *(const ushort4*)&Hs[(size_t)s * DIMC + cg];
    acc.x += bf2f(v.x); acc.y += bf2f(v.y); acc.z += bf2f(v.z); acc.w += bf2f(v.w);
  }
  acc.x += __shfl_xor(acc.x, 32, 64);
  acc.y += __shfl_xor(acc.y, 32, 64);
  acc.z += __shfl_xor(acc.z, 32, 64);
  acc.w += __shfl_xor(acc.w, 32, 64);
  if (slot == 0) {
    ushort4 sv = *(const ushort4*)&Hs[(size_t)node * DIMC + cg];
    float sc = inv[node];
    float4 b = *(const float4*)&bias[cg];
    float4 o;
    o.x = (acc.x + bf2f(sv.x)) * sc + b.x;
    o.y = (acc.y + bf2f(sv.y)) * sc + b.y;
    o.z = (acc.z + bf2f(sv.z)) * sc + b.z;
    o.w = (acc.w + bf2f(sv.w)) * sc + b.w;
    if (do_relu) {
      o.x = (o.x > 0.f) ? o.x : SLOPEF * o.x;
      o.y = (o.y > 0.f) ? o.y : SLOPEF * o.y;
      o.z = (o.z > 0.f) ? o.z : SLOPEF * o.z;
      o.w = (o.w > 0.f) ? o.w : SLOPEF * o.w;
    }
    *(float4*)&out[(size_t)node * DIMC + cg] = o;
  }
}

// ---------------- pooling ----------------
__global__ __launch_bounds__(128) void pool_kernel(const float* __restrict__ G, const int* __restrict__ batch,
                                                   float* __restrict__ psum, int* __restrict__ pcnt) {
  int t = threadIdx.x;
  int n0 = blockIdx.x * 64;
  int nend = min(n0 + 64, N_NODESC);
  int cur = batch[n0];
  float acc = 0.f;
  int c = 0;
  for (int n = n0; n < nend; ++n) {
    int b = batch[n];
    if (b != cur) {
      atomicAdd(&psum[cur * DIMC + t], acc);
      if (t == 0) atomicAdd(&pcnt[cur], c);
      acc = 0.f;
      c = 0;
      cur = b;
    }
    acc += G[(size_t)n * DIMC + t];
    c += 1;
  }
  atomicAdd(&psum[cur * DIMC + t], acc);
  if (t == 0) atomicAdd(&pcnt[cur], c);
}

__global__ __launch_bounds__(128) void mean_kernel(const float* __restrict__ psA, const int* __restrict__ pcA,
                                                   const float* __restrict__ psB, const int* __restrict__ pcB,
                                                   float* __restrict__ hA, float* __restrict__ hB) {
  int dir = blockIdx.x >> 6, g = blockIdx.x & 63, t = threadIdx.x;
  const float* ps = dir ? psB : psA;
  const int* pc = dir ? pcB : pcA;
  float* h = dir ? hB : hA;
  h[g * DIMC + t] = ps[g * DIMC + t] / (float)max(pc[g], 1);
}

// ---------------- attention (64 tokens per side) ----------------
__global__ __launch_bounds__(128) void qkv_kernel(const float* __restrict__ hA, const float* __restrict__ hB,
                                                  const float* __restrict__ Wq, const float* __restrict__ bq,
                                                  const float* __restrict__ Wk, const float* __restrict__ bk,
                                                  const float* __restrict__ Wv, const float* __restrict__ bv,
                                                  float* __restrict__ Q0, float* __restrict__ K0, float* __restrict__ V0,
                                                  float* __restrict__ Q1, float* __restrict__ K1, float* __restrict__ V1) {
  __shared__ float xs[DIMC];
  int task = blockIdx.x >> 6, r = blockIdx.x & 63, t = threadIdx.x;
  const float *X, *W, *b;
  float* Y;
  switch (task) {
    case 0: X = hA; W = Wq; b = bq; Y = Q0; break;
    case 1: X = hB; W = Wk; b = bk; Y = K0; break;
    case 2: X = hB; W = Wv; b = bv; Y = V0; break;
    case 3: X = hB; W = Wq; b = bq; Y = Q1; break;
    case 4: X = hA; W = Wk; b = bk; Y = K1; break;
    default: X = hA; W = Wv; b = bv; Y = V1; break;
  }
  xs[t] = X[r * DIMC + t];
  __syncthreads();
  float acc = b[t];
  for (int k = 0; k < DIMC; ++k) acc += xs[k] * W[k * DIMC + t];
  Y[r * DIMC + t] = acc;
}

__global__ __launch_bounds__(64) void attn_kernel(const float* __restrict__ Q0, const float* __restrict__ K0,
                                                  const float* __restrict__ V0, const float* __restrict__ Q1,
                                                  const float* __restrict__ K1, const float* __restrict__ V1,
                                                  float* __restrict__ O0, float* __restrict__ O1) {
  __shared__ float ps[64];
  int b = blockIdx.x;
  int dir = b >> 8, h = (b >> 6) & 3, q = b & 63;
  const float* Q = dir ? Q1 : Q0;
  const float* K = dir ? K1 : K0;
  const float* V = dir ? V1 : V0;
  float* O = dir ? O1 : O0;
  int k = threadIdx.x;
  const float* qp = Q + q * DIMC + h * HDC;
  const float* kp = K + k * DIMC + h * HDC;
  float s = 0.f;
#pragma unroll
  for (int d = 0; d < HDC; ++d) s += qp[d] * kp[d];
  s *= SCALEF;
  float m = s;
#pragma unroll
  for (int off = 32; off >= 1; off >>= 1) m = fmaxf(m, __shfl_xor(m, off, 64));
  float p = __expf(s - m);
  float sum = p;
#pragma unroll
  for (int off = 32; off >= 1; off >>= 1) sum += __shfl_xor(sum, off, 64);
  p /= sum;
  ps[k] = p;
  __syncthreads();
  int half = k >> 5, d = k & 31;
  float acc = 0.f;
#pragma unroll
  for (int j = 0; j < 32; ++j) {
    int kk = half * 32 + j;
    acc += ps[kk] * V[kk * DIMC + h * HDC + d];
  }
  acc += __shfl_xor(acc, 32, 64);
  if (half == 0) O[q * DIMC + h * HDC + d] = acc;
}

__device__ inline float blk_sum128(float v, float* red) {
#pragma unroll
  for (int off = 32; off >= 1; off >>= 1) v += __shfl_xor(v, off, 64);
  if ((threadIdx.x & 63) == 0) red[threadIdx.x >> 6] = v;
  __syncthreads();
  float r = red[0] + red[1];
  __syncthreads();
  return r;
}

__global__ __launch_bounds__(128) void oln_kernel(const float* __restrict__ O0, const float* __restrict__ O1,
                                                  const float* __restrict__ hA, const float* __restrict__ hB,
                                                  const float* __restrict__ Wo, const float* __restrict__ bo,
                                                  const float* __restrict__ g1, const float* __restrict__ be1,
                                                  float* __restrict__ X0, float* __restrict__ X1) {
  __shared__ float os[DIMC];
  __shared__ float red[2];
  int dir = blockIdx.x >> 6, q = blockIdx.x & 63, t = threadIdx.x;
  const float* O = dir ? O1 : O0;
  const float* xq = dir ? hB : hA;
  float* Xo = dir ? X1 : X0;
  os[t] = O[q * DIMC + t];
  __syncthreads();
  float acc = bo[t] + xq[q * DIMC + t];
  for (int k = 0; k < DIMC; ++k) acc += os[k] * Wo[k * DIMC + t];
  float mean = blk_sum128(acc, red) * (1.f / DIMC);
  float d = acc - mean;
  float var = blk_sum128(d * d, red) * (1.f / DIMC);
  Xo[q * DIMC + t] = d * rsqrtf(var + EPSF) * g1[t] + be1[t];
}

__global__ __launch_bounds__(256) void ff1_kernel(const float* __restrict__ X0, const float* __restrict__ X1,
                                                  const float* __restrict__ Wf1, const float* __restrict__ bf1,
                                                  float* __restrict__ F0, float* __restrict__ F1) {
  __shared__ float xs[DIMC];
  int dir = blockIdx.x >> 6, q = blockIdx.x & 63, t = threadIdx.x;
  const float* X = dir ? X1 : X0;
  float* F = dir ? F1 : F0;
  if (t < DIMC) xs[t] = X[q * DIMC + t];
  __syncthreads();
  float acc = bf1[t];
  for (int k = 0; k < DIMC; ++k) acc += xs[k] * Wf1[k * 256 + t];
  acc = (acc > 0.f) ? acc : SLOPEF * acc;
  F[q * 256 + t] = acc;
}

__global__ __launch_bounds__(128) void ffln_kernel(const float* __restrict__ F0, const float* __restrict__ F1,
                                                   const float* __restrict__ X0, const float* __restrict__ X1,
                                                   const float* __restrict__ Wf2, const float* __restrict__ bf2,
                                                   const float* __restrict__ g2, const float* __restrict__ be2,
                                                   float* __restrict__ Y0, float* __restrict__ Y1) {
  __shared__ float fs[256];
  __shared__ float red[2];
  int dir = blockIdx.x >> 6, q = blockIdx.x & 63, t = threadIdx.x;
  const float* F = dir ? F1 : F0;
  const float* X = dir ? X1 : X0;
  float* Y = dir ? Y1 : Y0;
  fs[t] = F[q * 256 + t];
  fs[t + 128] = F[q * 256 + t + 128];
  __syncthreads();
  float acc = bf2[t] + X[q * DIMC + t];
  for (int k = 0; k < 256; ++k) acc += fs[k] * Wf2[k * DIMC + t];
  float mean = blk_sum128(acc, red) * (1.f / DIMC);
  float d = acc - mean;
  float var = blk_sum128(d * d, red) * (1.f / DIMC);
  Y[q * DIMC + t] = d * rsqrtf(var + EPSF) * g2[t] + be2[t];
}

__global__ __launch_bounds__(128) void head_kernel(const float* __restrict__ Y0, const float* __restrict__ Y1,
                                                   const float* __restrict__ Wl1, const float* __restrict__ bl1,
                                                   const float* __restrict__ Wl2, const float* __restrict__ bl2,
                                                   float* __restrict__ out) {
  __shared__ float cs[256];
  __shared__ float red[2];
  int g = blockIdx.x, t = threadIdx.x;
  cs[t] = Y0[g * DIMC + t];
  cs[t + 128] = Y1[g * DIMC + t];
  __syncthreads();
  float acc = bl1[t];
  for (int k = 0; k < 256; ++k) acc += cs[k] * Wl1[k * DIMC + t];
  acc = fmaxf(acc, 0.f);
  float s = blk_sum128(acc * Wl2[t], red);
  if (t == 0) out[g] = s + bl2[0];
}

// ---------------- host ----------------
extern "C" void kernel_launch(void* const* d_in, const int* in_sizes, int n_in,
                              void* d_out, int out_size, void* d_ws, size_t ws_size,
                              hipStream_t stream) {
  const float* xA = (const float*)d_in[0];
  const float* xB = (const float*)d_in[1];
  const int* eiA = (const int*)d_in[2];
  const int* eiB = (const int*)d_in[3];
  const int* batA = (const int*)d_in[4];
  const int* batB = (const int*)d_in[5];
  const float* WA1 = (const float*)d_in[6];
  const float* WA2 = (const float*)d_in[7];
  const float* WB1 = (const float*)d_in[8];
  const float* WB2 = (const float*)d_in[9];
  const float* Wq = (const float*)d_in[10];
  const float* Wk = (const float*)d_in[11];
  const float* Wv = (const float*)d_in[12];
  const float* Wo = (const float*)d_in[13];
  const float* Wf1 = (const float*)d_in[14];
  const float* Wf2 = (const float*)d_in[15];
  const float* Wl1 = (const float*)d_in[16];
  const float* Wl2 = (const float*)d_in[17];
  const float* bA1 = (const float*)d_in[18];
  const float* bA2 = (const float*)d_in[19];
  const float* bB1 = (const float*)d_in[20];
  const float* bB2 = (const float*)d_in[21];
  const float* bq = (const float*)d_in[22];
  const float* bk = (const float*)d_in[23];
  const float* bv = (const float*)d_in[24];
  const float* bo = (const float*)d_in[25];
  const float* bf1 = (const float*)d_in[26];
  const float* bf2 = (const float*)d_in[27];
  const float* bl1 = (const float*)d_in[28];
  const float* bl2 = (const float*)d_in[29];
  const float* g1 = (const float*)d_in[30];
  const float* be1 = (const float*)d_in[31];
  const float* g2 = (const float*)d_in[32];
  const float* be2 = (const float*)d_in[33];

  char* base = (char*)d_ws;
  size_t off = 0;
  auto alloc = [&](size_t bytes) -> char* {
    char* r = base + off;
    off += (bytes + 255) & ~(size_t)255;
    return r;
  };
  unsigned short* h_buf = (unsigned short*)alloc((size_t)N_NODESC * DIMC * 2);  // bf16
  float* g_buf = (float*)alloc((size_t)N_NODESC * DIMC * 4);
  unsigned* packed = (unsigned*)alloc((size_t)N_EDGESC * 4);
  unsigned short* csr16 = (unsigned short*)alloc((size_t)N_EDGESC * 2);
  int* rowptr = (int*)alloc((size_t)(N_NODESC + 1) * 4);
  float* inv = (float*)alloc((size_t)N_NODESC * 4);
  int* hist = (int*)alloc((size_t)KBLK * NBUK * 4);
  int* bbase = (int*)alloc((size_t)KBLK * NBUK * 4);
  int* bucket_base = (int*)alloc((size_t)(NBUK + 1) * 4);
  unsigned short* wtbuf = (unsigned short*)alloc((size_t)4 * 2 * DIMC * DIMC * 2);  // 4 matrices x hi/lo
  size_t poff0 = off;
  float* psA = (float*)alloc(NGC * DIMC * 4);
  float* psB = (float*)alloc(NGC * DIMC * 4);
  int* pcA = (int*)alloc(NGC * 4);
  int* pcB = (int*)alloc(NGC * 4);
  size_t pbytes = off - poff0;  // pool region (zeroed once per call)
  float* mhA = (float*)alloc(NGC * DIMC * 4);
  float* mhB = (float*)alloc(NGC * DIMC * 4);
  float* Q0 = (float*)alloc(NGC * DIMC * 4);
  float* K0 = (float*)alloc(NGC * DIMC * 4);
  float* V0 = (float*)alloc(NGC * DIMC * 4);
  float* Q1 = (float*)alloc(NGC * DIMC * 4);
  float* K1 = (float*)alloc(NGC * DIMC * 4);
  float* V1 = (float*)alloc(NGC * DIMC * 4);
  float* O0 = (float*)alloc(NGC * DIMC * 4);
  float* O1 = (float*)alloc(NGC * DIMC * 4);
  float* X0 = (float*)alloc(NGC * DIMC * 4);
  float* X1 = (float*)alloc(NGC * DIMC * 4);
  float* F0 = (float*)alloc(NGC * 256 * 4);
  float* F1 = (float*)alloc(NGC * 256 * 4);
  float* Y0 = (float*)alloc(NGC * DIMC * 4);
  float* Y1 = (float*)alloc(NGC * DIMC * 4);

  hipMemsetAsync(base + poff0, 0, pbytes, stream);
  wconv<<<4, 256, 0, stream>>>(WA1, WA2, WB1, WB2, wtbuf);

  const int ggrid = (N_NODESC + 63) / 64;        // 782
  const int agrid = (N_NODESC + 3) / 4;          // 12500
  const int pgrid = (N_NODESC + 63) / 64;        // 782
  const size_t wmat = (size_t)2 * DIMC * DIMC;   // u16 elems per matrix slot (hi+lo)

  for (int side = 0; side < 2; ++side) {
    const float* x = side ? xB : xA;
    const int* ei = side ? eiB : eiA;
    const int* bat = side ? batB : batA;
    const float* b1 = side ? bB1 : bA1;
    const float* b2 = side ? bB2 : bA2;
    const unsigned short* Wt1 = wtbuf + (size_t)(side * 2 + 0) * wmat;
    const unsigned short* Wt2 = wtbuf + (size_t)(side * 2 + 1) * wmat;
    float* ps = side ? psB : psA;
    int* pc = side ? pcB : pcA;

    kbhist<<<KBLK, 1024, 0, stream>>>(ei, hist);
    kbscan<<<1, 1024, 0, stream>>>(hist, bbase, bucket_base);
    kbin<<<KBLK, 1024, 0, stream>>>(ei, bbase, packed);
    kcsr<<<NBUK, 256, 0, stream>>>(packed, bucket_base, csr16, rowptr, inv);
    gemm_mfma<<<ggrid, 256, 0, stream>>>(x, Wt1, inv, h_buf);
    agg_kernel<<<agrid, 256, 0, stream>>>(h_buf, inv, rowptr, csr16, b1, g_buf, 1);
    gemm_mfma<<<ggrid, 256, 0, stream>>>(g_buf, Wt2, inv, h_buf);
    agg_kernel<<<agrid, 256, 0, stream>>>(h_buf, inv, rowptr, csr16, b2, g_buf, 0);
    pool_kernel<<<pgrid, 128, 0, stream>>>(g_buf, bat, ps, pc);
  }

  mean_kernel<<<128, 128, 0, stream>>>(psA, pcA, psB, pcB, mhA, mhB);
  qkv_kernel<<<384, 128, 0, stream>>>(mhA, mhB, Wq, bq, Wk, bk, Wv, bv, Q0, K0, V0, Q1, K1, V1);
  attn_kernel<<<512, 64, 0, stream>>>(Q0, K0, V0, Q1, K1, V1, O0, O1);
  oln_kernel<<<128, 128, 0, stream>>>(O0, O1, mhA, mhB, Wo, bo, g1, be1, X0, X1);
  ff1_kernel<<<128, 256, 0, stream>>>(X0, X1, Wf1, bf1, F0, F1);
  ffln_kernel<<<128, 128, 0, stream>>>(F0, F1, X0, X1, Wf2, bf2, g2, be2, Y0, Y1);
  head_kernel<<<64, 128, 0, stream>>>(Y0, Y1, Wl1, bl1, Wl2, bl2, (float*)d_out);
}

// Round 8
// 415.348 us; speedup vs baseline: 1.1175x; 1.1175x over previous
//
#include <hip/hip_runtime.h>

#define N_NODESC 50000
#define N_EDGESC 800000
#define DIMC 128
#define NGC 64
#define HDC 32
#define SLOPEF 0.01f
#define EPSF 1e-5f
#define SCALEF 0.17677669529663687f  // 32^-0.5

#define NBUK 782   // ceil(50000/64) buckets of 64 dst nodes
#define KBLK 50    // binning blocks
#define EPB 16000  // edges per binning block (50*16000 = 800000)

typedef __attribute__((ext_vector_type(8))) short bf16x8;
typedef __attribute__((ext_vector_type(4))) float f32x4;

// fp32 <-> bf16 (RNE)
static __device__ __forceinline__ unsigned short f2bf(float f) {
  unsigned u = __float_as_uint(f);
  u = u + 0x7FFFu + ((u >> 16) & 1u);
  return (unsigned short)(u >> 16);
}
static __device__ __forceinline__ float bf2f(unsigned short h) {
  return __uint_as_float(((unsigned)h) << 16);
}

// ---------------- CSR build: locality-preserving two-level counting sort ----------------
__global__ __launch_bounds__(1024) void kbhist(const int* __restrict__ ei, int* __restrict__ hist) {
  __shared__ int lh[NBUK];
  int t = threadIdx.x;
  for (int i = t; i < NBUK; i += 1024) lh[i] = 0;
  __syncthreads();
  int e0 = blockIdx.x * EPB;
  for (int e = e0 + t; e < e0 + EPB; e += 1024) {
    int d = ei[N_EDGESC + e];
    atomicAdd(&lh[d >> 6], 1);
  }
  __syncthreads();
  for (int i = t; i < NBUK; i += 1024) hist[blockIdx.x * NBUK + i] = lh[i];
}

__global__ __launch_bounds__(1024) void kbscan(const int* __restrict__ hist, int* __restrict__ bbase,
                                               int* __restrict__ bucket_base) {
  __shared__ int sd[1024];
  int t = threadIdx.x;
  int tot = 0;
  if (t < NBUK) {
    for (int k = 0; k < KBLK; ++k) tot += hist[k * NBUK + t];
  }
  sd[t] = tot;
  __syncthreads();
  for (int off = 1; off < 1024; off <<= 1) {
    int u = (t >= off) ? sd[t - off] : 0;
    __syncthreads();
    sd[t] += u;
    __syncthreads();
  }
  if (t < NBUK) {
    int run = sd[t] - tot;  // exclusive bucket base
    bucket_base[t] = run;
    for (int k = 0; k < KBLK; ++k) {
      bbase[k * NBUK + t] = run;
      run += hist[k * NBUK + t];
    }
  }
  if (t == 0) bucket_base[NBUK] = N_EDGESC;
}

__global__ __launch_bounds__(1024) void kbin(const int* __restrict__ ei, const int* __restrict__ bbase,
                                             unsigned* __restrict__ packed) {
  __shared__ int cur[NBUK];
  int t = threadIdx.x;
  for (int i = t; i < NBUK; i += 1024) cur[i] = bbase[blockIdx.x * NBUK + i];
  __syncthreads();
  int e0 = blockIdx.x * EPB;
  for (int e = e0 + t; e < e0 + EPB; e += 1024) {
    int s = ei[e];
    int d = ei[N_EDGESC + e];
    int b = d >> 6;
    int pos = atomicAdd(&cur[b], 1);
    packed[pos] = (unsigned)s | ((unsigned)(d & 63) << 16);
  }
}

__global__ __launch_bounds__(256) void kcsr(const unsigned* __restrict__ packed, const int* __restrict__ bucket_base,
                                            unsigned short* __restrict__ csr16, int* __restrict__ rowptr,
                                            float* __restrict__ inv) {
  __shared__ int h64[64], o64[64], c64[64];
  int b = blockIdx.x, t = threadIdx.x;
  int beg = bucket_base[b], end = bucket_base[b + 1];
  if (t < 64) h64[t] = 0;
  __syncthreads();
  for (int e = beg + t; e < end; e += 256) atomicAdd(&h64[packed[e] >> 16], 1);
  __syncthreads();
  if (t == 0) {
    int run = 0;
    for (int j = 0; j < 64; ++j) { o64[j] = run; run += h64[j]; }
  }
  __syncthreads();
  if (t < 64) c64[t] = o64[t];
  __syncthreads();
  for (int e = beg + t; e < end; e += 256) {
    unsigned p = packed[e];
    int pos = atomicAdd(&c64[p >> 16], 1);
    csr16[beg + pos] = (unsigned short)(p & 0xFFFFu);
  }
  if (t < 64) {
    int node = b * 64 + t;
    if (node < N_NODESC) {
      rowptr[node] = beg + o64[t];
      inv[node] = rsqrtf((float)h64[t] + 1.0f);
    }
  }
  if (b == NBUK - 1 && t == 0) rowptr[N_NODESC] = N_EDGESC;
}

// ---------------- W pre-transform: fragment-major hi/lo bf16 ----------------
// Per matrix: 128 slots of 512 u16 (1KB). slot = (ks*8+nf)*2 + p (p: 0=hi,1=lo).
// Element [slot][lane][j] = Whi/lo[k][n] with k = ks*32 + (lane>>4)*8 + j, n = nf*16 + (lane&15).
// gemm loads slot base + lane*8 -> perfectly coalesced 1KB per B-frag.
__global__ __launch_bounds__(256) void wconv(const float* __restrict__ W0, const float* __restrict__ W1,
                                             const float* __restrict__ W2, const float* __restrict__ W3,
                                             unsigned short* __restrict__ Wt) {
  const float* W = (blockIdx.x == 0) ? W0 : (blockIdx.x == 1) ? W1 : (blockIdx.x == 2) ? W2 : W3;
  unsigned short* dst = Wt + (size_t)blockIdx.x * 128 * 512;
  for (int i = threadIdx.x; i < 128 * 512; i += 256) {
    int slot = i >> 9;
    int lane = (i >> 3) & 63;
    int j = i & 7;
    int p = slot & 1, fs = slot >> 1;
    int ks = fs >> 3, nf = fs & 7;
    int k = ks * 32 + (lane >> 4) * 8 + j;
    int n = nf * 16 + (lane & 15);
    float a = W[k * DIMC + n];
    unsigned short hi = f2bf(a);
    dst[i] = p ? f2bf(a - bf2f(hi)) : hi;
  }
}

// ---------------- encoder GEMM via MFMA: Y(bf16) = (X @ W) * inv[row] ----------------
// 4 waves/block, 64 rows/block. B from frag-major Wt (coalesced). hi+lo split -> W-quant ~2^-16.
// Epilogue: scale, LDS transpose [64][136] bf16, coalesced 256B/row global stores.
__global__ __launch_bounds__(256) void gemm_mfma(const float* __restrict__ X, const unsigned short* __restrict__ Wt,
                                                 const float* __restrict__ inv, unsigned short* __restrict__ Y) {
  __shared__ unsigned short lds[64 * 136];  // pad 8 u16 -> 272B row stride (16B aligned)
  int wave = threadIdx.x >> 6, lane = threadIdx.x & 63;
  int l15 = lane & 15, kb = lane >> 4;
  int row0 = blockIdx.x * 64 + wave * 16;
  int rA = row0 + l15;
  const bool valid = rA < N_NODESC;
  f32x4 acc[8];
#pragma unroll
  for (int nf = 0; nf < 8; ++nf) acc[nf] = 0.f;
#pragma unroll
  for (int ks = 0; ks < 4; ++ks) {
    int kbase = ks * 32 + kb * 8;
    bf16x8 a;
    if (valid) {
      const float* xp = &X[(size_t)rA * DIMC + kbase];
      float4 x0 = *(const float4*)xp;
      float4 x1 = *(const float4*)(xp + 4);
      a[0] = (short)f2bf(x0.x); a[1] = (short)f2bf(x0.y);
      a[2] = (short)f2bf(x0.z); a[3] = (short)f2bf(x0.w);
      a[4] = (short)f2bf(x1.x); a[5] = (short)f2bf(x1.y);
      a[6] = (short)f2bf(x1.z); a[7] = (short)f2bf(x1.w);
    } else {
      a = (short)0;
    }
    const unsigned short* wp = Wt + (size_t)(ks * 16) * 512 + lane * 8;
#pragma unroll
    for (int nf = 0; nf < 8; ++nf) {
      bf16x8 bh = *(const bf16x8*)(wp + (nf * 2) * 512);
      bf16x8 bl = *(const bf16x8*)(wp + (nf * 2 + 1) * 512);
      acc[nf] = __builtin_amdgcn_mfma_f32_16x16x32_bf16(a, bh, acc[nf], 0, 0, 0);
      acc[nf] = __builtin_amdgcn_mfma_f32_16x16x32_bf16(a, bl, acc[nf], 0, 0, 0);
    }
  }
  // scale + transpose into LDS
  int lrow = wave * 16 + kb * 4;
#pragma unroll
  for (int r = 0; r < 4; ++r) {
    int rr = row0 + kb * 4 + r;
    float s = (rr < N_NODESC) ? inv[rr] : 0.f;
#pragma unroll
    for (int nf = 0; nf < 8; ++nf) {
      lds[(lrow + r) * 136 + nf * 16 + l15] = f2bf(acc[nf][r] * s);
    }
  }
  __syncthreads();
  // coalesced store: 4 threads per row, 64B each
  int tr = threadIdx.x >> 2, c0 = (threadIdx.x & 3) * 32;
  int grow = blockIdx.x * 64 + tr;
  if (grow < N_NODESC) {
#pragma unroll
    for (int i = 0; i < 4; ++i) {
      *(uint4*)&Y[(size_t)grow * DIMC + c0 + i * 8] = *(const uint4*)&lds[tr * 136 + c0 + i * 8];
    }
  }
}

// ---------------- aggregation: out = (sum_{src} Hs[src] + Hs[i]) * inv[i] + b ----------------
__global__ __launch_bounds__(256) void agg_kernel(const unsigned short* __restrict__ Hs, const float* __restrict__ inv,
                                                  const int* __restrict__ rowptr, const unsigned short* __restrict__ csr,
                                                  const float* __restrict__ bias, float* __restrict__ out,
                                                  int do_relu) {
  int node = blockIdx.x * 4 + (threadIdx.x >> 6);
  if (node >= N_NODESC) return;
  int lane = threadIdx.x & 63;
  int cg = (lane & 31) * 4;
  int slot = lane >> 5;
  int beg = rowptr[node], end = rowptr[node + 1];
  float4 acc = make_float4(0.f, 0.f, 0.f, 0.f);
  int e = beg;
  for (; e + 8 <= end; e += 8) {
    int s0 = csr[e + slot];
    int s1 = csr[e + 2 + slot];
    int s2 = csr[e + 4 + slot];
    int s3 = csr[e + 6 + slot];
    ushort4 v0 = *(const ushort4*)&Hs[(size_t)s0 * DIMC + cg];
    ushort4 v1 = *(const ushort4*)&Hs[(size_t)s1 * DIMC + cg];
    ushort4 v2 = *(const ushort4*)&Hs[(size_t)s2 * DIMC + cg];
    ushort4 v3 = *(const ushort4*)&Hs[(size_t)s3 * DIMC + cg];
    acc.x += (bf2f(v0.x) + bf2f(v1.x)) + (bf2f(v2.x) + bf2f(v3.x));
    acc.y += (bf2f(v0.y) + bf2f(v1.y)) + (bf2f(v2.y) + bf2f(v3.y));
    acc.z += (bf2f(v0.z) + bf2f(v1.z)) + (bf2f(v2.z) + bf2f(v3.z));
    acc.w += (bf2f(v0.w) + bf2f(v1.w)) + (bf2f(v2.w) + bf2f(v3.w));
  }
  for (int t = e + slot; t < end; t += 2) {
    int s = csr[t];
    ushort4 v = *(const ushort4*)&Hs[(size_t)s * DIMC + cg];
    acc.x += bf2f(v.x); acc.y += bf2f(v.y); acc.z += bf2f(v.z); acc.w += bf2f(v.w);
  }
  acc.x += __shfl_xor(acc.x, 32, 64);
  acc.y += __shfl_xor(acc.y, 32, 64);
  acc.z += __shfl_xor(acc.z, 32, 64);
  acc.w += __shfl_xor(acc.w, 32, 64);
  if (slot == 0) {
    ushort4 sv = *(const ushort4*)&Hs[(size_t)node * DIMC + cg];
    float sc = inv[node];
    float4 b = *(const float4*)&bias[cg];
    float4 o;
    o.x = (acc.x + bf2f(sv.x)) * sc + b.x;
    o.y = (acc.y + bf2f(sv.y)) * sc + b.y;
    o.z = (acc.z + bf2f(sv.z)) * sc + b.z;
    o.w = (acc.w + bf2f(sv.w)) * sc + b.w;
    if (do_relu) {
      o.x = (o.x > 0.f) ? o.x : SLOPEF * o.x;
      o.y = (o.y > 0.f) ? o.y : SLOPEF * o.y;
      o.z = (o.z > 0.f) ? o.z : SLOPEF * o.z;
      o.w = (o.w > 0.f) ? o.w : SLOPEF * o.w;
    }
    *(float4*)&out[(size_t)node * DIMC + cg] = o;
  }
}

// ---------------- pooling ----------------
__global__ __launch_bounds__(128) void pool_kernel(const float* __restrict__ G, const int* __restrict__ batch,
                                                   float* __restrict__ psum, int* __restrict__ pcnt) {
  int t = threadIdx.x;
  int n0 = blockIdx.x * 64;
  int nend = min(n0 + 64, N_NODESC);
  int cur = batch[n0];
  float acc = 0.f;
  int c = 0;
  for (int n = n0; n < nend; ++n) {
    int b = batch[n];
    if (b != cur) {
      atomicAdd(&psum[cur * DIMC + t], acc);
      if (t == 0) atomicAdd(&pcnt[cur], c);
      acc = 0.f;
      c = 0;
      cur = b;
    }
    acc += G[(size_t)n * DIMC + t];
    c += 1;
  }
  atomicAdd(&psum[cur * DIMC + t], acc);
  if (t == 0) atomicAdd(&pcnt[cur], c);
}

__global__ __launch_bounds__(128) void mean_kernel(const float* __restrict__ psA, const int* __restrict__ pcA,
                                                   const float* __restrict__ psB, const int* __restrict__ pcB,
                                                   float* __restrict__ hA, float* __restrict__ hB) {
  int dir = blockIdx.x >> 6, g = blockIdx.x & 63, t = threadIdx.x;
  const float* ps = dir ? psB : psA;
  const int* pc = dir ? pcB : pcA;
  float* h = dir ? hB : hA;
  h[g * DIMC + t] = ps[g * DIMC + t] / (float)max(pc[g], 1);
}

// ---------------- attention (64 tokens per side) ----------------
__global__ __launch_bounds__(128) void qkv_kernel(const float* __restrict__ hA, const float* __restrict__ hB,
                                                  const float* __restrict__ Wq, const float* __restrict__ bq,
                                                  const float* __restrict__ Wk, const float* __restrict__ bk,
                                                  const float* __restrict__ Wv, const float* __restrict__ bv,
                                                  float* __restrict__ Q0, float* __restrict__ K0, float* __restrict__ V0,
                                                  float* __restrict__ Q1, float* __restrict__ K1, float* __restrict__ V1) {
  __shared__ float xs[DIMC];
  int task = blockIdx.x >> 6, r = blockIdx.x & 63, t = threadIdx.x;
  const float *X, *W, *b;
  float* Y;
  switch (task) {
    case 0: X = hA; W = Wq; b = bq; Y = Q0; break;
    case 1: X = hB; W = Wk; b = bk; Y = K0; break;
    case 2: X = hB; W = Wv; b = bv; Y = V0; break;
    case 3: X = hB; W = Wq; b = bq; Y = Q1; break;
    case 4: X = hA; W = Wk; b = bk; Y = K1; break;
    default: X = hA; W = Wv; b = bv; Y = V1; break;
  }
  xs[t] = X[r * DIMC + t];
  __syncthreads();
  float acc = b[t];
  for (int k = 0; k < DIMC; ++k) acc += xs[k] * W[k * DIMC + t];
  Y[r * DIMC + t] = acc;
}

__global__ __launch_bounds__(64) void attn_kernel(const float* __restrict__ Q0, const float* __restrict__ K0,
                                                  const float* __restrict__ V0, const float* __restrict__ Q1,
                                                  const float* __restrict__ K1, const float* __restrict__ V1,
                                                  float* __restrict__ O0, float* __restrict__ O1) {
  __shared__ float ps[64];
  int b = blockIdx.x;
  int dir = b >> 8, h = (b >> 6) & 3, q = b & 63;
  const float* Q = dir ? Q1 : Q0;
  const float* K = dir ? K1 : K0;
  const float* V = dir ? V1 : V0;
  float* O = dir ? O1 : O0;
  int k = threadIdx.x;
  const float* qp = Q + q * DIMC + h * HDC;
  const float* kp = K + k * DIMC + h * HDC;
  float s = 0.f;
#pragma unroll
  for (int d = 0; d < HDC; ++d) s += qp[d] * kp[d];
  s *= SCALEF;
  float m = s;
#pragma unroll
  for (int off = 32; off >= 1; off >>= 1) m = fmaxf(m, __shfl_xor(m, off, 64));
  float p = __expf(s - m);
  float sum = p;
#pragma unroll
  for (int off = 32; off >= 1; off >>= 1) sum += __shfl_xor(sum, off, 64);
  p /= sum;
  ps[k] = p;
  __syncthreads();
  int half = k >> 5, d = k & 31;
  float acc = 0.f;
#pragma unroll
  for (int j = 0; j < 32; ++j) {
    int kk = half * 32 + j;
    acc += ps[kk] * V[kk * DIMC + h * HDC + d];
  }
  acc += __shfl_xor(acc, 32, 64);
  if (half == 0) O[q * DIMC + h * HDC + d] = acc;
}

__device__ inline float blk_sum128(float v, float* red) {
#pragma unroll
  for (int off = 32; off >= 1; off >>= 1) v += __shfl_xor(v, off, 64);
  if ((threadIdx.x & 63) == 0) red[threadIdx.x >> 6] = v;
  __syncthreads();
  float r = red[0] + red[1];
  __syncthreads();
  return r;
}

__global__ __launch_bounds__(128) void oln_kernel(const float* __restrict__ O0, const float* __restrict__ O1,
                                                  const float* __restrict__ hA, const float* __restrict__ hB,
                                                  const float* __restrict__ Wo, const float* __restrict__ bo,
                                                  const float* __restrict__ g1, const float* __restrict__ be1,
                                                  float* __restrict__ X0, float* __restrict__ X1) {
  __shared__ float os[DIMC];
  __shared__ float red[2];
  int dir = blockIdx.x >> 6, q = blockIdx.x & 63, t = threadIdx.x;
  const float* O = dir ? O1 : O0;
  const float* xq = dir ? hB : hA;
  float* Xo = dir ? X1 : X0;
  os[t] = O[q * DIMC + t];
  __syncthreads();
  float acc = bo[t] + xq[q * DIMC + t];
  for (int k = 0; k < DIMC; ++k) acc += os[k] * Wo[k * DIMC + t];
  float mean = blk_sum128(acc, red) * (1.f / DIMC);
  float d = acc - mean;
  float var = blk_sum128(d * d, red) * (1.f / DIMC);
  Xo[q * DIMC + t] = d * rsqrtf(var + EPSF) * g1[t] + be1[t];
}

__global__ __launch_bounds__(256) void ff1_kernel(const float* __restrict__ X0, const float* __restrict__ X1,
                                                  const float* __restrict__ Wf1, const float* __restrict__ bf1,
                                                  float* __restrict__ F0, float* __restrict__ F1) {
  __shared__ float xs[DIMC];
  int dir = blockIdx.x >> 6, q = blockIdx.x & 63, t = threadIdx.x;
  const float* X = dir ? X1 : X0;
  float* F = dir ? F1 : F0;
  if (t < DIMC) xs[t] = X[q * DIMC + t];
  __syncthreads();
  float acc = bf1[t];
  for (int k = 0; k < DIMC; ++k) acc += xs[k] * Wf1[k * 256 + t];
  acc = (acc > 0.f) ? acc : SLOPEF * acc;
  F[q * 256 + t] = acc;
}

__global__ __launch_bounds__(128) void ffln_kernel(const float* __restrict__ F0, const float* __restrict__ F1,
                                                   const float* __restrict__ X0, const float* __restrict__ X1,
                                                   const float* __restrict__ Wf2, const float* __restrict__ bf2,
                                                   const float* __restrict__ g2, const float* __restrict__ be2,
                                                   float* __restrict__ Y0, float* __restrict__ Y1) {
  __shared__ float fs[256];
  __shared__ float red[2];
  int dir = blockIdx.x >> 6, q = blockIdx.x & 63, t = threadIdx.x;
  const float* F = dir ? F1 : F0;
  const float* X = dir ? X1 : X0;
  float* Y = dir ? Y1 : Y0;
  fs[t] = F[q * 256 + t];
  fs[t + 128] = F[q * 256 + t + 128];
  __syncthreads();
  float acc = bf2[t] + X[q * DIMC + t];
  for (int k = 0; k < 256; ++k) acc += fs[k] * Wf2[k * DIMC + t];
  float mean = blk_sum128(acc, red) * (1.f / DIMC);
  float d = acc - mean;
  float var = blk_sum128(d * d, red) * (1.f / DIMC);
  Y[q * DIMC + t] = d * rsqrtf(var + EPSF) * g2[t] + be2[t];
}

__global__ __launch_bounds__(128) void head_kernel(const float* __restrict__ Y0, const float* __restrict__ Y1,
                                                   const float* __restrict__ Wl1, const float* __restrict__ bl1,
                                                   const float* __restrict__ Wl2, const float* __restrict__ bl2,
                                                   float* __restrict__ out) {
  __shared__ float cs[256];
  __shared__ float red[2];
  int g = blockIdx.x, t = threadIdx.x;
  cs[t] = Y0[g * DIMC + t];
  cs[t + 128] = Y1[g * DIMC + t];
  __syncthreads();
  float acc = bl1[t];
  for (int k = 0; k < 256; ++k) acc += cs[k] * Wl1[k * DIMC + t];
  acc = fmaxf(acc, 0.f);
  float s = blk_sum128(acc * Wl2[t], red);
  if (t == 0) out[g] = s + bl2[0];
}

// ---------------- host ----------------
extern "C" void kernel_launch(void* const* d_in, const int* in_sizes, int n_in,
                              void* d_out, int out_size, void* d_ws, size_t ws_size,
                              hipStream_t stream) {
  const float* xA = (const float*)d_in[0];
  const float* xB = (const float*)d_in[1];
  const int* eiA = (const int*)d_in[2];
  const int* eiB = (const int*)d_in[3];
  const int* batA = (const int*)d_in[4];
  const int* batB = (const int*)d_in[5];
  const float* WA1 = (const float*)d_in[6];
  const float* WA2 = (const float*)d_in[7];
  const float* WB1 = (const float*)d_in[8];
  const float* WB2 = (const float*)d_in[9];
  const float* Wq = (const float*)d_in[10];
  const float* Wk = (const float*)d_in[11];
  const float* Wv = (const float*)d_in[12];
  const float* Wo = (const float*)d_in[13];
  const float* Wf1 = (const float*)d_in[14];
  const float* Wf2 = (const float*)d_in[15];
  const float* Wl1 = (const float*)d_in[16];
  const float* Wl2 = (const float*)d_in[17];
  const float* bA1 = (const float*)d_in[18];
  const float* bA2 = (const float*)d_in[19];
  const float* bB1 = (const float*)d_in[20];
  const float* bB2 = (const float*)d_in[21];
  const float* bq = (const float*)d_in[22];
  const float* bk = (const float*)d_in[23];
  const float* bv = (const float*)d_in[24];
  const float* bo = (const float*)d_in[25];
  const float* bf1 = (const float*)d_in[26];
  const float* bf2 = (const float*)d_in[27];
  const float* bl1 = (const float*)d_in[28];
  const float* bl2 = (const float*)d_in[29];
  const float* g1 = (const float*)d_in[30];
  const float* be1 = (const float*)d_in[31];
  const float* g2 = (const float*)d_in[32];
  const float* be2 = (const float*)d_in[33];

  char* base = (char*)d_ws;
  size_t off = 0;
  auto alloc = [&](size_t bytes) -> char* {
    char* r = base + off;
    off += (bytes + 255) & ~(size_t)255;
    return r;
  };
  unsigned short* h_buf = (unsigned short*)alloc((size_t)N_NODESC * DIMC * 2);  // bf16
  float* g_buf = (float*)alloc((size_t)N_NODESC * DIMC * 4);
  unsigned* packed = (unsigned*)alloc((size_t)N_EDGESC * 4);
  unsigned short* csr16 = (unsigned short*)alloc((size_t)N_EDGESC * 2);
  int* rowptr = (int*)alloc((size_t)(N_NODESC + 1) * 4);
  float* inv = (float*)alloc((size_t)N_NODESC * 4);
  int* hist = (int*)alloc((size_t)KBLK * NBUK * 4);
  int* bbase = (int*)alloc((size_t)KBLK * NBUK * 4);
  int* bucket_base = (int*)alloc((size_t)(NBUK + 1) * 4);
  unsigned short* wtbuf = (unsigned short*)alloc((size_t)4 * 128 * 512 * 2);  // 4 matrices, frag-major hi/lo
  size_t poff0 = off;
  float* psA = (float*)alloc(NGC * DIMC * 4);
  float* psB = (float*)alloc(NGC * DIMC * 4);
  int* pcA = (int*)alloc(NGC * 4);
  int* pcB = (int*)alloc(NGC * 4);
  size_t pbytes = off - poff0;  // pool region (zeroed once per call)
  float* mhA = (float*)alloc(NGC * DIMC * 4);
  float* mhB = (float*)alloc(NGC * DIMC * 4);
  float* Q0 = (float*)alloc(NGC * DIMC * 4);
  float* K0 = (float*)alloc(NGC * DIMC * 4);
  float* V0 = (float*)alloc(NGC * DIMC * 4);
  float* Q1 = (float*)alloc(NGC * DIMC * 4);
  float* K1 = (float*)alloc(NGC * DIMC * 4);
  float* V1 = (float*)alloc(NGC * DIMC * 4);
  float* O0 = (float*)alloc(NGC * DIMC * 4);
  float* O1 = (float*)alloc(NGC * DIMC * 4);
  float* X0 = (float*)alloc(NGC * DIMC * 4);
  float* X1 = (float*)alloc(NGC * DIMC * 4);
  float* F0 = (float*)alloc(NGC * 256 * 4);
  float* F1 = (float*)alloc(NGC * 256 * 4);
  float* Y0 = (float*)alloc(NGC * DIMC * 4);
  float* Y1 = (float*)alloc(NGC * DIMC * 4);

  hipMemsetAsync(base + poff0, 0, pbytes, stream);
  wconv<<<4, 256, 0, stream>>>(WA1, WA2, WB1, WB2, wtbuf);

  const int ggrid = (N_NODESC + 63) / 64;        // 782
  const int agrid = (N_NODESC + 3) / 4;          // 12500
  const int pgrid = (N_NODESC + 63) / 64;        // 782
  const size_t wmat = (size_t)128 * 512;         // u16 elems per matrix slot

  for (int side = 0; side < 2; ++side) {
    const float* x = side ? xB : xA;
    const int* ei = side ? eiB : eiA;
    const int* bat = side ? batB : batA;
    const float* b1 = side ? bB1 : bA1;
    const float* b2 = side ? bB2 : bA2;
    const unsigned short* Wt1 = wtbuf + (size_t)(side * 2 + 0) * wmat;
    const unsigned short* Wt2 = wtbuf + (size_t)(side * 2 + 1) * wmat;
    float* ps = side ? psB : psA;
    int* pc = side ? pcB : pcA;

    kbhist<<<KBLK, 1024, 0, stream>>>(ei, hist);
    kbscan<<<1, 1024, 0, stream>>>(hist, bbase, bucket_base);
    kbin<<<KBLK, 1024, 0, stream>>>(ei, bbase, packed);
    kcsr<<<NBUK, 256, 0, stream>>>(packed, bucket_base, csr16, rowptr, inv);
    gemm_mfma<<<ggrid, 256, 0, stream>>>(x, Wt1, inv, h_buf);
    agg_kernel<<<agrid, 256, 0, stream>>>(h_buf, inv, rowptr, csr16, b1, g_buf, 1);
    gemm_mfma<<<ggrid, 256, 0, stream>>>(g_buf, Wt2, inv, h_buf);
    agg_kernel<<<agrid, 256, 0, stream>>>(h_buf, inv, rowptr, csr16, b2, g_buf, 0);
    pool_kernel<<<pgrid, 128, 0, stream>>>(g_buf, bat, ps, pc);
  }

  mean_kernel<<<128, 128, 0, stream>>>(psA, pcA, psB, pcB, mhA, mhB);
  qkv_kernel<<<384, 128, 0, stream>>>(mhA, mhB, Wq, bq, Wk, bk, Wv, bv, Q0, K0, V0, Q1, K1, V1);
  attn_kernel<<<512, 64, 0, stream>>>(Q0, K0, V0, Q1, K1, V1, O0, O1);
  oln_kernel<<<128, 128, 0, stream>>>(O0, O1, mhA, mhB, Wo, bo, g1, be1, X0, X1);
  ff1_kernel<<<128, 256, 0, stream>>>(X0, X1, Wf1, bf1, F0, F1);
  ffln_kernel<<<128, 128, 0, stream>>>(F0, F1, X0, X1, Wf2, bf2, g2, be2, Y0, Y1);
  head_kernel<<<64, 128, 0, stream>>>(Y0, Y1, Wl1, bl1, Wl2, bl2, (float*)d_out);
}

// Round 9
// 381.284 us; speedup vs baseline: 1.2173x; 1.0893x over previous
//
#include <hip/hip_runtime.h>

#define N_NODESC 50000
#define N_EDGESC 800000
#define DIMC 128
#define NGC 64
#define HDC 32
#define SLOPEF 0.01f
#define EPSF 1e-5f
#define SCALEF 0.17677669529663687f  // 32^-0.5

#define NBUK 782   // ceil(50000/64) buckets of 64 dst nodes
#define KBLK 50    // binning blocks
#define EPB 16000  // edges per binning block (50*16000 = 800000)

typedef __attribute__((ext_vector_type(8))) short bf16x8;
typedef __attribute__((ext_vector_type(4))) float f32x4;

// fp32 <-> bf16 (RNE)
static __device__ __forceinline__ unsigned short f2bf(float f) {
  unsigned u = __float_as_uint(f);
  u = u + 0x7FFFu + ((u >> 16) & 1u);
  return (unsigned short)(u >> 16);
}
static __device__ __forceinline__ float bf2f(unsigned short h) {
  return __uint_as_float(((unsigned)h) << 16);
}

// ---------------- CSR build: locality-preserving two-level counting sort ----------------
__global__ __launch_bounds__(1024) void kbhist(const int* __restrict__ ei, int* __restrict__ hist) {
  __shared__ int lh[NBUK];
  int t = threadIdx.x;
  for (int i = t; i < NBUK; i += 1024) lh[i] = 0;
  __syncthreads();
  int e0 = blockIdx.x * EPB;
  for (int e = e0 + t; e < e0 + EPB; e += 1024) {
    int d = ei[N_EDGESC + e];
    atomicAdd(&lh[d >> 6], 1);
  }
  __syncthreads();
  for (int i = t; i < NBUK; i += 1024) hist[blockIdx.x * NBUK + i] = lh[i];
}

__global__ __launch_bounds__(1024) void kbscan(const int* __restrict__ hist, int* __restrict__ bbase,
                                               int* __restrict__ bucket_base) {
  __shared__ int sd[1024];
  int t = threadIdx.x;
  int tot = 0;
  if (t < NBUK) {
    for (int k = 0; k < KBLK; ++k) tot += hist[k * NBUK + t];
  }
  sd[t] = tot;
  __syncthreads();
  for (int off = 1; off < 1024; off <<= 1) {
    int u = (t >= off) ? sd[t - off] : 0;
    __syncthreads();
    sd[t] += u;
    __syncthreads();
  }
  if (t < NBUK) {
    int run = sd[t] - tot;  // exclusive bucket base
    bucket_base[t] = run;
    for (int k = 0; k < KBLK; ++k) {
      bbase[k * NBUK + t] = run;
      run += hist[k * NBUK + t];
    }
  }
  if (t == 0) bucket_base[NBUK] = N_EDGESC;
}

__global__ __launch_bounds__(1024) void kbin(const int* __restrict__ ei, const int* __restrict__ bbase,
                                             unsigned* __restrict__ packed) {
  __shared__ int cur[NBUK];
  int t = threadIdx.x;
  for (int i = t; i < NBUK; i += 1024) cur[i] = bbase[blockIdx.x * NBUK + i];
  __syncthreads();
  int e0 = blockIdx.x * EPB;
  for (int e = e0 + t; e < e0 + EPB; e += 1024) {
    int s = ei[e];
    int d = ei[N_EDGESC + e];
    int b = d >> 6;
    int pos = atomicAdd(&cur[b], 1);
    packed[pos] = (unsigned)s | ((unsigned)(d & 63) << 16);
  }
}

__global__ __launch_bounds__(256) void kcsr(const unsigned* __restrict__ packed, const int* __restrict__ bucket_base,
                                            unsigned short* __restrict__ csr16, int* __restrict__ rowptr,
                                            float* __restrict__ inv) {
  __shared__ int h64[64], o64[64], c64[64];
  int b = blockIdx.x, t = threadIdx.x;
  int beg = bucket_base[b], end = bucket_base[b + 1];
  if (t < 64) h64[t] = 0;
  __syncthreads();
  for (int e = beg + t; e < end; e += 256) atomicAdd(&h64[packed[e] >> 16], 1);
  __syncthreads();
  if (t == 0) {
    int run = 0;
    for (int j = 0; j < 64; ++j) { o64[j] = run; run += h64[j]; }
  }
  __syncthreads();
  if (t < 64) c64[t] = o64[t];
  __syncthreads();
  for (int e = beg + t; e < end; e += 256) {
    unsigned p = packed[e];
    int pos = atomicAdd(&c64[p >> 16], 1);
    csr16[beg + pos] = (unsigned short)(p & 0xFFFFu);
  }
  if (t < 64) {
    int node = b * 64 + t;
    if (node < N_NODESC) {
      rowptr[node] = beg + o64[t];
      inv[node] = rsqrtf((float)h64[t] + 1.0f);
    }
  }
  if (b == NBUK - 1 && t == 0) rowptr[N_NODESC] = N_EDGESC;
}

// ---------------- W pre-transform: fragment-major hi/lo bf16 ----------------
// Per matrix: 128 slots of 512 u16 (1KB). slot = (ks*8+nf)*2 + p (p: 0=hi,1=lo).
// Element [slot][lane][j] = Whi/lo[k][n] with k = ks*32 + (lane>>4)*8 + j, n = nf*16 + (lane&15).
// 64 blocks: one thread per (fs,lane) computes hi+lo (8 reads in flight, 2x16B coalesced writes).
__global__ __launch_bounds__(256) void wconv(const float* __restrict__ W0, const float* __restrict__ W1,
                                             const float* __restrict__ W2, const float* __restrict__ W3,
                                             unsigned short* __restrict__ Wt) {
  int m = blockIdx.x >> 4;                              // matrix 0..3
  int idx = (blockIdx.x & 15) * 256 + threadIdx.x;      // 0..4095: (fs,lane)
  int fs = idx >> 6, lane = idx & 63;
  int ks = fs >> 3, nf = fs & 7;
  int n = nf * 16 + (lane & 15);
  int k0 = ks * 32 + (lane >> 4) * 8;
  const float* W = (m == 0) ? W0 : (m == 1) ? W1 : (m == 2) ? W2 : W3;
  unsigned short* hi = Wt + (size_t)m * 128 * 512 + (size_t)(fs * 2) * 512 + lane * 8;
  bf16x8 vh, vl;
#pragma unroll
  for (int j = 0; j < 8; ++j) {
    float a = W[(k0 + j) * DIMC + n];
    unsigned short h = f2bf(a);
    vh[j] = (short)h;
    vl[j] = (short)f2bf(a - bf2f(h));
  }
  *(bf16x8*)hi = vh;
  *(bf16x8*)(hi + 512) = vl;
}

// ---------------- encoder GEMM via MFMA: Y(bf16) = (X @ W) * inv[row] ----------------
// 4 waves/block, 64 rows/block. B from frag-major Wt (coalesced). hi+lo split -> W-quant ~2^-16.
// Epilogue: scale, LDS transpose [64][136] bf16, coalesced 256B/row global stores.
__global__ __launch_bounds__(256) void gemm_mfma(const float* __restrict__ X, const unsigned short* __restrict__ Wt,
                                                 const float* __restrict__ inv, unsigned short* __restrict__ Y) {
  __shared__ unsigned short lds[64 * 136];  // pad 8 u16 -> 272B row stride (16B aligned)
  int wave = threadIdx.x >> 6, lane = threadIdx.x & 63;
  int l15 = lane & 15, kb = lane >> 4;
  int row0 = blockIdx.x * 64 + wave * 16;
  int rA = row0 + l15;
  const bool valid = rA < N_NODESC;
  f32x4 acc[8];
#pragma unroll
  for (int nf = 0; nf < 8; ++nf) acc[nf] = 0.f;
#pragma unroll
  for (int ks = 0; ks < 4; ++ks) {
    int kbase = ks * 32 + kb * 8;
    bf16x8 a;
    if (valid) {
      const float* xp = &X[(size_t)rA * DIMC + kbase];
      float4 x0 = *(const float4*)xp;
      float4 x1 = *(const float4*)(xp + 4);
      a[0] = (short)f2bf(x0.x); a[1] = (short)f2bf(x0.y);
      a[2] = (short)f2bf(x0.z); a[3] = (short)f2bf(x0.w);
      a[4] = (short)f2bf(x1.x); a[5] = (short)f2bf(x1.y);
      a[6] = (short)f2bf(x1.z); a[7] = (short)f2bf(x1.w);
    } else {
      a = (short)0;
    }
    const unsigned short* wp = Wt + (size_t)(ks * 16) * 512 + lane * 8;
#pragma unroll
    for (int nf = 0; nf < 8; ++nf) {
      bf16x8 bh = *(const bf16x8*)(wp + (nf * 2) * 512);
      bf16x8 bl = *(const bf16x8*)(wp + (nf * 2 + 1) * 512);
      acc[nf] = __builtin_amdgcn_mfma_f32_16x16x32_bf16(a, bh, acc[nf], 0, 0, 0);
      acc[nf] = __builtin_amdgcn_mfma_f32_16x16x32_bf16(a, bl, acc[nf], 0, 0, 0);
    }
  }
  // scale + transpose into LDS
  int lrow = wave * 16 + kb * 4;
#pragma unroll
  for (int r = 0; r < 4; ++r) {
    int rr = row0 + kb * 4 + r;
    float s = (rr < N_NODESC) ? inv[rr] : 0.f;
#pragma unroll
    for (int nf = 0; nf < 8; ++nf) {
      lds[(lrow + r) * 136 + nf * 16 + l15] = f2bf(acc[nf][r] * s);
    }
  }
  __syncthreads();
  // coalesced store: 4 threads per row, 64B each
  int tr = threadIdx.x >> 2, c0 = (threadIdx.x & 3) * 32;
  int grow = blockIdx.x * 64 + tr;
  if (grow < N_NODESC) {
#pragma unroll
    for (int i = 0; i < 4; ++i) {
      *(uint4*)&Y[(size_t)grow * DIMC + c0 + i * 8] = *(const uint4*)&lds[tr * 136 + c0 + i * 8];
    }
  }
}

// ---------------- aggregation: out = (sum_{src} Hs[src] + Hs[i]) * inv[i] + b ----------------
__global__ __launch_bounds__(256) void agg_kernel(const unsigned short* __restrict__ Hs, const float* __restrict__ inv,
                                                  const int* __restrict__ rowptr, const unsigned short* __restrict__ csr,
                                                  const float* __restrict__ bias, float* __restrict__ out,
                                                  int do_relu) {
  int node = blockIdx.x * 4 + (threadIdx.x >> 6);
  if (node >= N_NODESC) return;
  int lane = threadIdx.x & 63;
  int cg = (lane & 31) * 4;
  int slot = lane >> 5;
  int beg = rowptr[node], end = rowptr[node + 1];
  float4 acc = make_float4(0.f, 0.f, 0.f, 0.f);
  int e = beg;
  for (; e + 8 <= end; e += 8) {
    int s0 = csr[e + slot];
    int s1 = csr[e + 2 + slot];
    int s2 = csr[e + 4 + slot];
    int s3 = csr[e + 6 + slot];
    ushort4 v0 = *(const ushort4*)&Hs[(size_t)s0 * DIMC + cg];
    ushort4 v1 = *(const ushort4*)&Hs[(size_t)s1 * DIMC + cg];
    ushort4 v2 = *(const ushort4*)&Hs[(size_t)s2 * DIMC + cg];
    ushort4 v3 = *(const ushort4*)&Hs[(size_t)s3 * DIMC + cg];
    acc.x += (bf2f(v0.x) + bf2f(v1.x)) + (bf2f(v2.x) + bf2f(v3.x));
    acc.y += (bf2f(v0.y) + bf2f(v1.y)) + (bf2f(v2.y) + bf2f(v3.y));
    acc.z += (bf2f(v0.z) + bf2f(v1.z)) + (bf2f(v2.z) + bf2f(v3.z));
    acc.w += (bf2f(v0.w) + bf2f(v1.w)) + (bf2f(v2.w) + bf2f(v3.w));
  }
  for (int t = e + slot; t < end; t += 2) {
    int s = csr[t];
    ushort4 v = *(const ushort4*)&Hs[(size_t)s * DIMC + cg];
    acc.x += bf2f(v.x); acc.y += bf2f(v.y); acc.z += bf2f(v.z); acc.w += bf2f(v.w);
  }
  acc.x += __shfl_xor(acc.x, 32, 64);
  acc.y += __shfl_xor(acc.y, 32, 64);
  acc.z += __shfl_xor(acc.z, 32, 64);
  acc.w += __shfl_xor(acc.w, 32, 64);
  if (slot == 0) {
    ushort4 sv = *(const ushort4*)&Hs[(size_t)node * DIMC + cg];
    float sc = inv[node];
    float4 b = *(const float4*)&bias[cg];
    float4 o;
    o.x = (acc.x + bf2f(sv.x)) * sc + b.x;
    o.y = (acc.y + bf2f(sv.y)) * sc + b.y;
    o.z = (acc.z + bf2f(sv.z)) * sc + b.z;
    o.w = (acc.w + bf2f(sv.w)) * sc + b.w;
    if (do_relu) {
      o.x = (o.x > 0.f) ? o.x : SLOPEF * o.x;
      o.y = (o.y > 0.f) ? o.y : SLOPEF * o.y;
      o.z = (o.z > 0.f) ? o.z : SLOPEF * o.z;
      o.w = (o.w > 0.f) ? o.w : SLOPEF * o.w;
    }
    *(float4*)&out[(size_t)node * DIMC + cg] = o;
  }
}

// ---------------- pooling ----------------
__global__ __launch_bounds__(128) void pool_kernel(const float* __restrict__ G, const int* __restrict__ batch,
                                                   float* __restrict__ psum, int* __restrict__ pcnt) {
  int t = threadIdx.x;
  int n0 = blockIdx.x * 64;
  int nend = min(n0 + 64, N_NODESC);
  int cur = batch[n0];
  float acc = 0.f;
  int c = 0;
  for (int n = n0; n < nend; ++n) {
    int b = batch[n];
    if (b != cur) {
      atomicAdd(&psum[cur * DIMC + t], acc);
      if (t == 0) atomicAdd(&pcnt[cur], c);
      acc = 0.f;
      c = 0;
      cur = b;
    }
    acc += G[(size_t)n * DIMC + t];
    c += 1;
  }
  atomicAdd(&psum[cur * DIMC + t], acc);
  if (t == 0) atomicAdd(&pcnt[cur], c);
}

__global__ __launch_bounds__(128) void mean_kernel(const float* __restrict__ psA, const int* __restrict__ pcA,
                                                   const float* __restrict__ psB, const int* __restrict__ pcB,
                                                   float* __restrict__ hA, float* __restrict__ hB) {
  int dir = blockIdx.x >> 6, g = blockIdx.x & 63, t = threadIdx.x;
  const float* ps = dir ? psB : psA;
  const int* pc = dir ? pcB : pcA;
  float* h = dir ? hB : hA;
  h[g * DIMC + t] = ps[g * DIMC + t] / (float)max(pc[g], 1);
}

// ---------------- attention (64 tokens per side) ----------------
__global__ __launch_bounds__(128) void qkv_kernel(const float* __restrict__ hA, const float* __restrict__ hB,
                                                  const float* __restrict__ Wq, const float* __restrict__ bq,
                                                  const float* __restrict__ Wk, const float* __restrict__ bk,
                                                  const float* __restrict__ Wv, const float* __restrict__ bv,
                                                  float* __restrict__ Q0, float* __restrict__ K0, float* __restrict__ V0,
                                                  float* __restrict__ Q1, float* __restrict__ K1, float* __restrict__ V1) {
  __shared__ float xs[DIMC];
  int task = blockIdx.x >> 6, r = blockIdx.x & 63, t = threadIdx.x;
  const float *X, *W, *b;
  float* Y;
  switch (task) {
    case 0: X = hA; W = Wq; b = bq; Y = Q0; break;
    case 1: X = hB; W = Wk; b = bk; Y = K0; break;
    case 2: X = hB; W = Wv; b = bv; Y = V0; break;
    case 3: X = hB; W = Wq; b = bq; Y = Q1; break;
    case 4: X = hA; W = Wk; b = bk; Y = K1; break;
    default: X = hA; W = Wv; b = bv; Y = V1; break;
  }
  xs[t] = X[r * DIMC + t];
  __syncthreads();
  float acc = b[t];
  for (int k = 0; k < DIMC; ++k) acc += xs[k] * W[k * DIMC + t];
  Y[r * DIMC + t] = acc;
}

__global__ __launch_bounds__(64) void attn_kernel(const float* __restrict__ Q0, const float* __restrict__ K0,
                                                  const float* __restrict__ V0, const float* __restrict__ Q1,
                                                  const float* __restrict__ K1, const float* __restrict__ V1,
                                                  float* __restrict__ O0, float* __restrict__ O1) {
  __shared__ float ps[64];
  int b = blockIdx.x;
  int dir = b >> 8, h = (b >> 6) & 3, q = b & 63;
  const float* Q = dir ? Q1 : Q0;
  const float* K = dir ? K1 : K0;
  const float* V = dir ? V1 : V0;
  float* O = dir ? O1 : O0;
  int k = threadIdx.x;
  const float* qp = Q + q * DIMC + h * HDC;
  const float* kp = K + k * DIMC + h * HDC;
  float s = 0.f;
#pragma unroll
  for (int d = 0; d < HDC; ++d) s += qp[d] * kp[d];
  s *= SCALEF;
  float m = s;
#pragma unroll
  for (int off = 32; off >= 1; off >>= 1) m = fmaxf(m, __shfl_xor(m, off, 64));
  float p = __expf(s - m);
  float sum = p;
#pragma unroll
  for (int off = 32; off >= 1; off >>= 1) sum += __shfl_xor(sum, off, 64);
  p /= sum;
  ps[k] = p;
  __syncthreads();
  int half = k >> 5, d = k & 31;
  float acc = 0.f;
#pragma unroll
  for (int j = 0; j < 32; ++j) {
    int kk = half * 32 + j;
    acc += ps[kk] * V[kk * DIMC + h * HDC + d];
  }
  acc += __shfl_xor(acc, 32, 64);
  if (half == 0) O[q * DIMC + h * HDC + d] = acc;
}

__device__ inline float blk_sum128(float v, float* red) {
#pragma unroll
  for (int off = 32; off >= 1; off >>= 1) v += __shfl_xor(v, off, 64);
  if ((threadIdx.x & 63) == 0) red[threadIdx.x >> 6] = v;
  __syncthreads();
  float r = red[0] + red[1];
  __syncthreads();
  return r;
}

__global__ __launch_bounds__(128) void oln_kernel(const float* __restrict__ O0, const float* __restrict__ O1,
                                                  const float* __restrict__ hA, const float* __restrict__ hB,
                                                  const float* __restrict__ Wo, const float* __restrict__ bo,
                                                  const float* __restrict__ g1, const float* __restrict__ be1,
                                                  float* __restrict__ X0, float* __restrict__ X1) {
  __shared__ float os[DIMC];
  __shared__ float red[2];
  int dir = blockIdx.x >> 6, q = blockIdx.x & 63, t = threadIdx.x;
  const float* O = dir ? O1 : O0;
  const float* xq = dir ? hB : hA;
  float* Xo = dir ? X1 : X0;
  os[t] = O[q * DIMC + t];
  __syncthreads();
  float acc = bo[t] + xq[q * DIMC + t];
  for (int k = 0; k < DIMC; ++k) acc += os[k] * Wo[k * DIMC + t];
  float mean = blk_sum128(acc, red) * (1.f / DIMC);
  float d = acc - mean;
  float var = blk_sum128(d * d, red) * (1.f / DIMC);
  Xo[q * DIMC + t] = d * rsqrtf(var + EPSF) * g1[t] + be1[t];
}

__global__ __launch_bounds__(256) void ff1_kernel(const float* __restrict__ X0, const float* __restrict__ X1,
                                                  const float* __restrict__ Wf1, const float* __restrict__ bf1,
                                                  float* __restrict__ F0, float* __restrict__ F1) {
  __shared__ float xs[DIMC];
  int dir = blockIdx.x >> 6, q = blockIdx.x & 63, t = threadIdx.x;
  const float* X = dir ? X1 : X0;
  float* F = dir ? F1 : F0;
  if (t < DIMC) xs[t] = X[q * DIMC + t];
  __syncthreads();
  float acc = bf1[t];
  for (int k = 0; k < DIMC; ++k) acc += xs[k] * Wf1[k * 256 + t];
  acc = (acc > 0.f) ? acc : SLOPEF * acc;
  F[q * 256 + t] = acc;
}

__global__ __launch_bounds__(128) void ffln_kernel(const float* __restrict__ F0, const float* __restrict__ F1,
                                                   const float* __restrict__ X0, const float* __restrict__ X1,
                                                   const float* __restrict__ Wf2, const float* __restrict__ bf2,
                                                   const float* __restrict__ g2, const float* __restrict__ be2,
                                                   float* __restrict__ Y0, float* __restrict__ Y1) {
  __shared__ float fs[256];
  __shared__ float red[2];
  int dir = blockIdx.x >> 6, q = blockIdx.x & 63, t = threadIdx.x;
  const float* F = dir ? F1 : F0;
  const float* X = dir ? X1 : X0;
  float* Y = dir ? Y1 : Y0;
  fs[t] = F[q * 256 + t];
  fs[t + 128] = F[q * 256 + t + 128];
  __syncthreads();
  float acc = bf2[t] + X[q * DIMC + t];
  for (int k = 0; k < 256; ++k) acc += fs[k] * Wf2[k * DIMC + t];
  float mean = blk_sum128(acc, red) * (1.f / DIMC);
  float d = acc - mean;
  float var = blk_sum128(d * d, red) * (1.f / DIMC);
  Y[q * DIMC + t] = d * rsqrtf(var + EPSF) * g2[t] + be2[t];
}

__global__ __launch_bounds__(128) void head_kernel(const float* __restrict__ Y0, const float* __restrict__ Y1,
                                                   const float* __restrict__ Wl1, const float* __restrict__ bl1,
                                                   const float* __restrict__ Wl2, const float* __restrict__ bl2,
                                                   float* __restrict__ out) {
  __shared__ float cs[256];
  __shared__ float red[2];
  int g = blockIdx.x, t = threadIdx.x;
  cs[t] = Y0[g * DIMC + t];
  cs[t + 128] = Y1[g * DIMC + t];
  __syncthreads();
  float acc = bl1[t];
  for (int k = 0; k < 256; ++k) acc += cs[k] * Wl1[k * DIMC + t];
  acc = fmaxf(acc, 0.f);
  float s = blk_sum128(acc * Wl2[t], red);
  if (t == 0) out[g] = s + bl2[0];
}

// ---------------- host ----------------
extern "C" void kernel_launch(void* const* d_in, const int* in_sizes, int n_in,
                              void* d_out, int out_size, void* d_ws, size_t ws_size,
                              hipStream_t stream) {
  const float* xA = (const float*)d_in[0];
  const float* xB = (const float*)d_in[1];
  const int* eiA = (const int*)d_in[2];
  const int* eiB = (const int*)d_in[3];
  const int* batA = (const int*)d_in[4];
  const int* batB = (const int*)d_in[5];
  const float* WA1 = (const float*)d_in[6];
  const float* WA2 = (const float*)d_in[7];
  const float* WB1 = (const float*)d_in[8];
  const float* WB2 = (const float*)d_in[9];
  const float* Wq = (const float*)d_in[10];
  const float* Wk = (const float*)d_in[11];
  const float* Wv = (const float*)d_in[12];
  const float* Wo = (const float*)d_in[13];
  const float* Wf1 = (const float*)d_in[14];
  const float* Wf2 = (const float*)d_in[15];
  const float* Wl1 = (const float*)d_in[16];
  const float* Wl2 = (const float*)d_in[17];
  const float* bA1 = (const float*)d_in[18];
  const float* bA2 = (const float*)d_in[19];
  const float* bB1 = (const float*)d_in[20];
  const float* bB2 = (const float*)d_in[21];
  const float* bq = (const float*)d_in[22];
  const float* bk = (const float*)d_in[23];
  const float* bv = (const float*)d_in[24];
  const float* bo = (const float*)d_in[25];
  const float* bf1 = (const float*)d_in[26];
  const float* bf2 = (const float*)d_in[27];
  const float* bl1 = (const float*)d_in[28];
  const float* bl2 = (const float*)d_in[29];
  const float* g1 = (const float*)d_in[30];
  const float* be1 = (const float*)d_in[31];
  const float* g2 = (const float*)d_in[32];
  const float* be2 = (const float*)d_in[33];

  char* base = (char*)d_ws;
  size_t off = 0;
  auto alloc = [&](size_t bytes) -> char* {
    char* r = base + off;
    off += (bytes + 255) & ~(size_t)255;
    return r;
  };
  unsigned short* h_buf = (unsigned short*)alloc((size_t)N_NODESC * DIMC * 2);  // bf16
  float* g_buf = (float*)alloc((size_t)N_NODESC * DIMC * 4);
  unsigned* packed = (unsigned*)alloc((size_t)N_EDGESC * 4);
  unsigned short* csr16 = (unsigned short*)alloc((size_t)N_EDGESC * 2);
  int* rowptr = (int*)alloc((size_t)(N_NODESC + 1) * 4);
  float* inv = (float*)alloc((size_t)N_NODESC * 4);
  int* hist = (int*)alloc((size_t)KBLK * NBUK * 4);
  int* bbase = (int*)alloc((size_t)KBLK * NBUK * 4);
  int* bucket_base = (int*)alloc((size_t)(NBUK + 1) * 4);
  unsigned short* wtbuf = (unsigned short*)alloc((size_t)4 * 128 * 512 * 2);  // 4 matrices, frag-major hi/lo
  size_t poff0 = off;
  float* psA = (float*)alloc(NGC * DIMC * 4);
  float* psB = (float*)alloc(NGC * DIMC * 4);
  int* pcA = (int*)alloc(NGC * 4);
  int* pcB = (int*)alloc(NGC * 4);
  size_t pbytes = off - poff0;  // pool region (zeroed once per call)
  float* mhA = (float*)alloc(NGC * DIMC * 4);
  float* mhB = (float*)alloc(NGC * DIMC * 4);
  float* Q0 = (float*)alloc(NGC * DIMC * 4);
  float* K0 = (float*)alloc(NGC * DIMC * 4);
  float* V0 = (float*)alloc(NGC * DIMC * 4);
  float* Q1 = (float*)alloc(NGC * DIMC * 4);
  float* K1 = (float*)alloc(NGC * DIMC * 4);
  float* V1 = (float*)alloc(NGC * DIMC * 4);
  float* O0 = (float*)alloc(NGC * DIMC * 4);
  float* O1 = (float*)alloc(NGC * DIMC * 4);
  float* X0 = (float*)alloc(NGC * DIMC * 4);
  float* X1 = (float*)alloc(NGC * DIMC * 4);
  float* F0 = (float*)alloc(NGC * 256 * 4);
  float* F1 = (float*)alloc(NGC * 256 * 4);
  float* Y0 = (float*)alloc(NGC * DIMC * 4);
  float* Y1 = (float*)alloc(NGC * DIMC * 4);

  hipMemsetAsync(base + poff0, 0, pbytes, stream);
  wconv<<<64, 256, 0, stream>>>(WA1, WA2, WB1, WB2, wtbuf);

  const int ggrid = (N_NODESC + 63) / 64;        // 782
  const int agrid = (N_NODESC + 3) / 4;          // 12500
  const int pgrid = (N_NODESC + 63) / 64;        // 782
  const size_t wmat = (size_t)128 * 512;         // u16 elems per matrix slot

  for (int side = 0; side < 2; ++side) {
    const float* x = side ? xB : xA;
    const int* ei = side ? eiB : eiA;
    const int* bat = side ? batB : batA;
    const float* b1 = side ? bB1 : bA1;
    const float* b2 = side ? bB2 : bA2;
    const unsigned short* Wt1 = wtbuf + (size_t)(side * 2 + 0) * wmat;
    const unsigned short* Wt2 = wtbuf + (size_t)(side * 2 + 1) * wmat;
    float* ps = side ? psB : psA;
    int* pc = side ? pcB : pcA;

    kbhist<<<KBLK, 1024, 0, stream>>>(ei, hist);
    kbscan<<<1, 1024, 0, stream>>>(hist, bbase, bucket_base);
    kbin<<<KBLK, 1024, 0, stream>>>(ei, bbase, packed);
    kcsr<<<NBUK, 256, 0, stream>>>(packed, bucket_base, csr16, rowptr, inv);
    gemm_mfma<<<ggrid, 256, 0, stream>>>(x, Wt1, inv, h_buf);
    agg_kernel<<<agrid, 256, 0, stream>>>(h_buf, inv, rowptr, csr16, b1, g_buf, 1);
    gemm_mfma<<<ggrid, 256, 0, stream>>>(g_buf, Wt2, inv, h_buf);
    agg_kernel<<<agrid, 256, 0, stream>>>(h_buf, inv, rowptr, csr16, b2, g_buf, 0);
    pool_kernel<<<pgrid, 128, 0, stream>>>(g_buf, bat, ps, pc);
  }

  mean_kernel<<<128, 128, 0, stream>>>(psA, pcA, psB, pcB, mhA, mhB);
  qkv_kernel<<<384, 128, 0, stream>>>(mhA, mhB, Wq, bq, Wk, bk, Wv, bv, Q0, K0, V0, Q1, K1, V1);
  attn_kernel<<<512, 64, 0, stream>>>(Q0, K0, V0, Q1, K1, V1, O0, O1);
  oln_kernel<<<128, 128, 0, stream>>>(O0, O1, mhA, mhB, Wo, bo, g1, be1, X0, X1);
  ff1_kernel<<<128, 256, 0, stream>>>(X0, X1, Wf1, bf1, F0, F1);
  ffln_kernel<<<128, 128, 0, stream>>>(F0, F1, X0, X1, Wf2, bf2, g2, be2, Y0, Y1);
  head_kernel<<<64, 128, 0, stream>>>(Y0, Y1, Wl1, bl1, Wl2, bl2, (float*)d_out);
}

// Round 10
// 295.648 us; speedup vs baseline: 1.5699x; 1.2897x over previous
//
#include <hip/hip_runtime.h>

#define N_NODESC 50000
#define N_EDGESC 800000
#define DIMC 128
#define NGC 64
#define HDC 32
#define SLOPEF 0.01f
#define EPSF 1e-5f
#define SCALEF 0.17677669529663687f  // 32^-0.5

#define NBUK 782   // ceil(50000/64) buckets of 64 dst nodes
#define KBLK 50    // binning blocks per side
#define EPB 16000  // edges per binning block (50*16000 = 800000)
#define GG 782     // gemm/pool blocks per side (64 rows each)
#define AG 12500   // agg blocks per side (4 nodes each)

typedef __attribute__((ext_vector_type(8))) short bf16x8;
typedef __attribute__((ext_vector_type(4))) float f32x4;

// fp32 <-> bf16 (RNE)
static __device__ __forceinline__ unsigned short f2bf(float f) {
  unsigned u = __float_as_uint(f);
  u = u + 0x7FFFu + ((u >> 16) & 1u);
  return (unsigned short)(u >> 16);
}
static __device__ __forceinline__ float bf2f(unsigned short h) {
  return __uint_as_float(((unsigned)h) << 16);
}

// ---------------- CSR build (both sides per launch) ----------------
__global__ __launch_bounds__(1024) void kbhist2(const int* __restrict__ eiA, const int* __restrict__ eiB,
                                                int* __restrict__ hist) {
  __shared__ int lh[NBUK];
  int side = blockIdx.x / KBLK, blk = blockIdx.x % KBLK;
  const int* ei = side ? eiB : eiA;
  int* hout = hist + side * KBLK * NBUK;
  int t = threadIdx.x;
  for (int i = t; i < NBUK; i += 1024) lh[i] = 0;
  __syncthreads();
  int e0 = blk * EPB;
  for (int e = e0 + t; e < e0 + EPB; e += 1024) {
    int d = ei[N_EDGESC + e];
    atomicAdd(&lh[d >> 6], 1);
  }
  __syncthreads();
  for (int i = t; i < NBUK; i += 1024) hout[blk * NBUK + i] = lh[i];
}

__global__ __launch_bounds__(1024) void kbscan2(const int* __restrict__ hist, int* __restrict__ bbase,
                                                int* __restrict__ bucket_base) {
  __shared__ int sd[1024];
  int side = blockIdx.x;
  const int* h = hist + side * KBLK * NBUK;
  int* bb = bbase + side * KBLK * NBUK;
  int* bub = bucket_base + side * (NBUK + 1);
  int t = threadIdx.x;
  int tot = 0;
  if (t < NBUK) {
    for (int k = 0; k < KBLK; ++k) tot += h[k * NBUK + t];
  }
  sd[t] = tot;
  __syncthreads();
  for (int off = 1; off < 1024; off <<= 1) {
    int u = (t >= off) ? sd[t - off] : 0;
    __syncthreads();
    sd[t] += u;
    __syncthreads();
  }
  if (t < NBUK) {
    int run = sd[t] - tot;  // exclusive bucket base
    bub[t] = run;
    for (int k = 0; k < KBLK; ++k) {
      bb[k * NBUK + t] = run;
      run += h[k * NBUK + t];
    }
  }
  if (t == 0) bub[NBUK] = N_EDGESC;
}

__global__ __launch_bounds__(1024) void kbin2(const int* __restrict__ eiA, const int* __restrict__ eiB,
                                              const int* __restrict__ bbase, unsigned* __restrict__ packed) {
  __shared__ int cur[NBUK];
  int side = blockIdx.x / KBLK, blk = blockIdx.x % KBLK;
  const int* ei = side ? eiB : eiA;
  const int* bb = bbase + side * KBLK * NBUK;
  unsigned* pk = packed + (size_t)side * N_EDGESC;
  int t = threadIdx.x;
  for (int i = t; i < NBUK; i += 1024) cur[i] = bb[blk * NBUK + i];
  __syncthreads();
  int e0 = blk * EPB;
  for (int e = e0 + t; e < e0 + EPB; e += 1024) {
    int s = ei[e];
    int d = ei[N_EDGESC + e];
    int b = d >> 6;
    int pos = atomicAdd(&cur[b], 1);
    pk[pos] = (unsigned)s | ((unsigned)(d & 63) << 16);
  }
}

__global__ __launch_bounds__(256) void kcsr2(const unsigned* __restrict__ packed, const int* __restrict__ bucket_base,
                                             unsigned short* __restrict__ csr16, int* __restrict__ rowptr,
                                             float* __restrict__ inv) {
  __shared__ int h64[64], o64[64], c64[64];
  int side = blockIdx.x / NBUK, b = blockIdx.x % NBUK;
  const unsigned* pk = packed + (size_t)side * N_EDGESC;
  const int* bub = bucket_base + side * (NBUK + 1);
  unsigned short* cs = csr16 + (size_t)side * N_EDGESC;
  int* rp = rowptr + side * (N_NODESC + 1);
  float* iv = inv + side * N_NODESC;
  int t = threadIdx.x;
  int beg = bub[b], end = bub[b + 1];
  if (t < 64) h64[t] = 0;
  __syncthreads();
  for (int e = beg + t; e < end; e += 256) atomicAdd(&h64[pk[e] >> 16], 1);
  __syncthreads();
  if (t == 0) {
    int run = 0;
    for (int j = 0; j < 64; ++j) { o64[j] = run; run += h64[j]; }
  }
  __syncthreads();
  if (t < 64) c64[t] = o64[t];
  __syncthreads();
  for (int e = beg + t; e < end; e += 256) {
    unsigned p = pk[e];
    int pos = atomicAdd(&c64[p >> 16], 1);
    cs[beg + pos] = (unsigned short)(p & 0xFFFFu);
  }
  if (t < 64) {
    int node = b * 64 + t;
    if (node < N_NODESC) {
      rp[node] = beg + o64[t];
      iv[node] = rsqrtf((float)h64[t] + 1.0f);
    }
  }
  if (b == NBUK - 1 && t == 0) rp[N_NODESC] = N_EDGESC;
}

// ---------------- W pre-transform: fragment-major hi/lo bf16 ----------------
__global__ __launch_bounds__(256) void wconv(const float* __restrict__ W0, const float* __restrict__ W1,
                                             const float* __restrict__ W2, const float* __restrict__ W3,
                                             unsigned short* __restrict__ Wt) {
  int m = blockIdx.x >> 4;                              // matrix 0..3
  int idx = (blockIdx.x & 15) * 256 + threadIdx.x;      // 0..4095: (fs,lane)
  int fs = idx >> 6, lane = idx & 63;
  int ks = fs >> 3, nf = fs & 7;
  int n = nf * 16 + (lane & 15);
  int k0 = ks * 32 + (lane >> 4) * 8;
  const float* W = (m == 0) ? W0 : (m == 1) ? W1 : (m == 2) ? W2 : W3;
  unsigned short* hi = Wt + (size_t)m * 128 * 512 + (size_t)(fs * 2) * 512 + lane * 8;
  bf16x8 vh, vl;
#pragma unroll
  for (int j = 0; j < 8; ++j) {
    float a = W[(k0 + j) * DIMC + n];
    unsigned short h = f2bf(a);
    vh[j] = (short)h;
    vl[j] = (short)f2bf(a - bf2f(h));
  }
  *(bf16x8*)hi = vh;
  *(bf16x8*)(hi + 512) = vl;
}

// ---------------- GEMM layer1 (fp32 in): h(bf16) = (X @ W1) * inv ----------------
__global__ __launch_bounds__(256) void gemm_l1(const float* __restrict__ xA, const float* __restrict__ xB,
                                               const unsigned short* __restrict__ Wt, const float* __restrict__ inv,
                                               unsigned short* __restrict__ H) {
  __shared__ unsigned short lds[64 * 136];
  int side = blockIdx.x / GG, lb = blockIdx.x % GG;
  const float* X = side ? xB : xA;
  const unsigned short* Wm = Wt + (size_t)(side * 2) * 128 * 512;
  const float* iv = inv + side * N_NODESC;
  unsigned short* Y = H + (size_t)side * N_NODESC * DIMC;
  int wave = threadIdx.x >> 6, lane = threadIdx.x & 63;
  int l15 = lane & 15, kb = lane >> 4;
  int row0 = lb * 64 + wave * 16;
  int rA = row0 + l15;
  const bool valid = rA < N_NODESC;
  f32x4 acc[8];
#pragma unroll
  for (int nf = 0; nf < 8; ++nf) acc[nf] = 0.f;
#pragma unroll
  for (int ks = 0; ks < 4; ++ks) {
    int kbase = ks * 32 + kb * 8;
    bf16x8 a;
    if (valid) {
      const float* xp = &X[(size_t)rA * DIMC + kbase];
      float4 x0 = *(const float4*)xp;
      float4 x1 = *(const float4*)(xp + 4);
      a[0] = (short)f2bf(x0.x); a[1] = (short)f2bf(x0.y);
      a[2] = (short)f2bf(x0.z); a[3] = (short)f2bf(x0.w);
      a[4] = (short)f2bf(x1.x); a[5] = (short)f2bf(x1.y);
      a[6] = (short)f2bf(x1.z); a[7] = (short)f2bf(x1.w);
    } else {
      a = (short)0;
    }
    const unsigned short* wp = Wm + (size_t)(ks * 16) * 512 + lane * 8;
#pragma unroll
    for (int nf = 0; nf < 8; ++nf) {
      bf16x8 bh = *(const bf16x8*)(wp + (nf * 2) * 512);
      bf16x8 bl = *(const bf16x8*)(wp + (nf * 2 + 1) * 512);
      acc[nf] = __builtin_amdgcn_mfma_f32_16x16x32_bf16(a, bh, acc[nf], 0, 0, 0);
      acc[nf] = __builtin_amdgcn_mfma_f32_16x16x32_bf16(a, bl, acc[nf], 0, 0, 0);
    }
  }
  int lrow = wave * 16 + kb * 4;
#pragma unroll
  for (int r = 0; r < 4; ++r) {
    int rr = row0 + kb * 4 + r;
    float s = (rr < N_NODESC) ? iv[rr] : 0.f;
#pragma unroll
    for (int nf = 0; nf < 8; ++nf) {
      lds[(lrow + r) * 136 + nf * 16 + l15] = f2bf(acc[nf][r] * s);
    }
  }
  __syncthreads();
  int tr = threadIdx.x >> 2, c0 = (threadIdx.x & 3) * 32;
  int grow = lb * 64 + tr;
  if (grow < N_NODESC) {
#pragma unroll
    for (int i = 0; i < 4; ++i) {
      *(uint4*)&Y[(size_t)grow * DIMC + c0 + i * 8] = *(const uint4*)&lds[tr * 136 + c0 + i * 8];
    }
  }
}

// ---------------- GEMM layer2 (bf16 in): h(bf16) = (G @ W2) * inv ----------------
__global__ __launch_bounds__(256) void gemm_l2(const unsigned short* __restrict__ Gb,
                                               const unsigned short* __restrict__ Wt, const float* __restrict__ inv,
                                               unsigned short* __restrict__ H) {
  __shared__ unsigned short lds[64 * 136];
  int side = blockIdx.x / GG, lb = blockIdx.x % GG;
  const unsigned short* X = Gb + (size_t)side * N_NODESC * DIMC;
  const unsigned short* Wm = Wt + (size_t)(side * 2 + 1) * 128 * 512;
  const float* iv = inv + side * N_NODESC;
  unsigned short* Y = H + (size_t)side * N_NODESC * DIMC;
  int wave = threadIdx.x >> 6, lane = threadIdx.x & 63;
  int l15 = lane & 15, kb = lane >> 4;
  int row0 = lb * 64 + wave * 16;
  int rA = row0 + l15;
  const bool valid = rA < N_NODESC;
  f32x4 acc[8];
#pragma unroll
  for (int nf = 0; nf < 8; ++nf) acc[nf] = 0.f;
#pragma unroll
  for (int ks = 0; ks < 4; ++ks) {
    int kbase = ks * 32 + kb * 8;
    bf16x8 a;
    if (valid) {
      a = *(const bf16x8*)&X[(size_t)rA * DIMC + kbase];
    } else {
      a = (short)0;
    }
    const unsigned short* wp = Wm + (size_t)(ks * 16) * 512 + lane * 8;
#pragma unroll
    for (int nf = 0; nf < 8; ++nf) {
      bf16x8 bh = *(const bf16x8*)(wp + (nf * 2) * 512);
      bf16x8 bl = *(const bf16x8*)(wp + (nf * 2 + 1) * 512);
      acc[nf] = __builtin_amdgcn_mfma_f32_16x16x32_bf16(a, bh, acc[nf], 0, 0, 0);
      acc[nf] = __builtin_amdgcn_mfma_f32_16x16x32_bf16(a, bl, acc[nf], 0, 0, 0);
    }
  }
  int lrow = wave * 16 + kb * 4;
#pragma unroll
  for (int r = 0; r < 4; ++r) {
    int rr = row0 + kb * 4 + r;
    float s = (rr < N_NODESC) ? iv[rr] : 0.f;
#pragma unroll
    for (int nf = 0; nf < 8; ++nf) {
      lds[(lrow + r) * 136 + nf * 16 + l15] = f2bf(acc[nf][r] * s);
    }
  }
  __syncthreads();
  int tr = threadIdx.x >> 2, c0 = (threadIdx.x & 3) * 32;
  int grow = lb * 64 + tr;
  if (grow < N_NODESC) {
#pragma unroll
    for (int i = 0; i < 4; ++i) {
      *(uint4*)&Y[(size_t)grow * DIMC + c0 + i * 8] = *(const uint4*)&lds[tr * 136 + c0 + i * 8];
    }
  }
}

// ---------------- aggregation (both sides): g(bf16) = leaky?((sum + self)*inv + b) ----------------
__global__ __launch_bounds__(256) void agg12(const unsigned short* __restrict__ H, const float* __restrict__ inv,
                                             const int* __restrict__ rowptr, const unsigned short* __restrict__ csr16,
                                             const float* __restrict__ biasA, const float* __restrict__ biasB,
                                             unsigned short* __restrict__ G, int do_relu) {
  int side = blockIdx.x / AG, lb = blockIdx.x % AG;
  int node = lb * 4 + (threadIdx.x >> 6);
  if (node >= N_NODESC) return;
  const unsigned short* Hs = H + (size_t)side * N_NODESC * DIMC;
  const float* iv = inv + side * N_NODESC;
  const int* rp = rowptr + side * (N_NODESC + 1);
  const unsigned short* csr = csr16 + (size_t)side * N_EDGESC;
  const float* bias = side ? biasB : biasA;
  unsigned short* out = G + (size_t)side * N_NODESC * DIMC;
  int lane = threadIdx.x & 63;
  int cg = (lane & 31) * 4;
  int slot = lane >> 5;
  int beg = rp[node], end = rp[node + 1];
  float4 acc = make_float4(0.f, 0.f, 0.f, 0.f);
  int e = beg;
  for (; e + 8 <= end; e += 8) {
    int s0 = csr[e + slot];
    int s1 = csr[e + 2 + slot];
    int s2 = csr[e + 4 + slot];
    int s3 = csr[e + 6 + slot];
    ushort4 v0 = *(const ushort4*)&Hs[(size_t)s0 * DIMC + cg];
    ushort4 v1 = *(const ushort4*)&Hs[(size_t)s1 * DIMC + cg];
    ushort4 v2 = *(const ushort4*)&Hs[(size_t)s2 * DIMC + cg];
    ushort4 v3 = *(const ushort4*)&Hs[(size_t)s3 * DIMC + cg];
    acc.x += (bf2f(v0.x) + bf2f(v1.x)) + (bf2f(v2.x) + bf2f(v3.x));
    acc.y += (bf2f(v0.y) + bf2f(v1.y)) + (bf2f(v2.y) + bf2f(v3.y));
    acc.z += (bf2f(v0.z) + bf2f(v1.z)) + (bf2f(v2.z) + bf2f(v3.z));
    acc.w += (bf2f(v0.w) + bf2f(v1.w)) + (bf2f(v2.w) + bf2f(v3.w));
  }
  for (int t = e + slot; t < end; t += 2) {
    int s = csr[t];
    ushort4 v = *(const ushort4*)&Hs[(size_t)s * DIMC + cg];
    acc.x += bf2f(v.x); acc.y += bf2f(v.y); acc.z += bf2f(v.z); acc.w += bf2f(v.w);
  }
  acc.x += __shfl_xor(acc.x, 32, 64);
  acc.y += __shfl_xor(acc.y, 32, 64);
  acc.z += __shfl_xor(acc.z, 32, 64);
  acc.w += __shfl_xor(acc.w, 32, 64);
  if (slot == 0) {
    ushort4 sv = *(const ushort4*)&Hs[(size_t)node * DIMC + cg];
    float sc = iv[node];
    float4 b = *(const float4*)&bias[cg];
    float4 o;
    o.x = (acc.x + bf2f(sv.x)) * sc + b.x;
    o.y = (acc.y + bf2f(sv.y)) * sc + b.y;
    o.z = (acc.z + bf2f(sv.z)) * sc + b.z;
    o.w = (acc.w + bf2f(sv.w)) * sc + b.w;
    if (do_relu) {
      o.x = (o.x > 0.f) ? o.x : SLOPEF * o.x;
      o.y = (o.y > 0.f) ? o.y : SLOPEF * o.y;
      o.z = (o.z > 0.f) ? o.z : SLOPEF * o.z;
      o.w = (o.w > 0.f) ? o.w : SLOPEF * o.w;
    }
    ushort4 ob;
    ob.x = f2bf(o.x); ob.y = f2bf(o.y); ob.z = f2bf(o.z); ob.w = f2bf(o.w);
    *(ushort4*)&out[(size_t)node * DIMC + cg] = ob;
  }
}

// ---------------- pooling (both sides, bf16 in) ----------------
__global__ __launch_bounds__(128) void pool2(const unsigned short* __restrict__ G,
                                             const int* __restrict__ batA, const int* __restrict__ batB,
                                             float* __restrict__ psA, float* __restrict__ psB,
                                             int* __restrict__ pcA, int* __restrict__ pcB) {
  int side = blockIdx.x / GG, lb = blockIdx.x % GG;
  const unsigned short* g = G + (size_t)side * N_NODESC * DIMC;
  const int* batch = side ? batB : batA;
  float* psum = side ? psB : psA;
  int* pcnt = side ? pcB : pcA;
  int t = threadIdx.x;
  int n0 = lb * 64;
  int nend = min(n0 + 64, N_NODESC);
  int cur = batch[n0];
  float acc = 0.f;
  int c = 0;
  for (int n = n0; n < nend; ++n) {
    int b = batch[n];
    if (b != cur) {
      atomicAdd(&psum[cur * DIMC + t], acc);
      if (t == 0) atomicAdd(&pcnt[cur], c);
      acc = 0.f;
      c = 0;
      cur = b;
    }
    acc += bf2f(g[(size_t)n * DIMC + t]);
    c += 1;
  }
  atomicAdd(&psum[cur * DIMC + t], acc);
  if (t == 0) atomicAdd(&pcnt[cur], c);
}

__global__ __launch_bounds__(128) void mean_kernel(const float* __restrict__ psA, const int* __restrict__ pcA,
                                                   const float* __restrict__ psB, const int* __restrict__ pcB,
                                                   float* __restrict__ hA, float* __restrict__ hB) {
  int dir = blockIdx.x >> 6, g = blockIdx.x & 63, t = threadIdx.x;
  const float* ps = dir ? psB : psA;
  const int* pc = dir ? pcB : pcA;
  float* h = dir ? hB : hA;
  h[g * DIMC + t] = ps[g * DIMC + t] / (float)max(pc[g], 1);
}

// ---------------- attention (64 tokens per side) ----------------
__global__ __launch_bounds__(128) void qkv_kernel(const float* __restrict__ hA, const float* __restrict__ hB,
                                                  const float* __restrict__ Wq, const float* __restrict__ bq,
                                                  const float* __restrict__ Wk, const float* __restrict__ bk,
                                                  const float* __restrict__ Wv, const float* __restrict__ bv,
                                                  float* __restrict__ Q0, float* __restrict__ K0, float* __restrict__ V0,
                                                  float* __restrict__ Q1, float* __restrict__ K1, float* __restrict__ V1) {
  __shared__ float xs[DIMC];
  int task = blockIdx.x >> 6, r = blockIdx.x & 63, t = threadIdx.x;
  const float *X, *W, *b;
  float* Y;
  switch (task) {
    case 0: X = hA; W = Wq; b = bq; Y = Q0; break;
    case 1: X = hB; W = Wk; b = bk; Y = K0; break;
    case 2: X = hB; W = Wv; b = bv; Y = V0; break;
    case 3: X = hB; W = Wq; b = bq; Y = Q1; break;
    case 4: X = hA; W = Wk; b = bk; Y = K1; break;
    default: X = hA; W = Wv; b = bv; Y = V1; break;
  }
  xs[t] = X[r * DIMC + t];
  __syncthreads();
  float acc = b[t];
  for (int k = 0; k < DIMC; ++k) acc += xs[k] * W[k * DIMC + t];
  Y[r * DIMC + t] = acc;
}

__global__ __launch_bounds__(64) void attn_kernel(const float* __restrict__ Q0, const float* __restrict__ K0,
                                                  const float* __restrict__ V0, const float* __restrict__ Q1,
                                                  const float* __restrict__ K1, const float* __restrict__ V1,
                                                  float* __restrict__ O0, float* __restrict__ O1) {
  __shared__ float ps[64];
  int b = blockIdx.x;
  int dir = b >> 8, h = (b >> 6) & 3, q = b & 63;
  const float* Q = dir ? Q1 : Q0;
  const float* K = dir ? K1 : K0;
  const float* V = dir ? V1 : V0;
  float* O = dir ? O1 : O0;
  int k = threadIdx.x;
  const float* qp = Q + q * DIMC + h * HDC;
  const float* kp = K + k * DIMC + h * HDC;
  float s = 0.f;
#pragma unroll
  for (int d = 0; d < HDC; ++d) s += qp[d] * kp[d];
  s *= SCALEF;
  float m = s;
#pragma unroll
  for (int off = 32; off >= 1; off >>= 1) m = fmaxf(m, __shfl_xor(m, off, 64));
  float p = __expf(s - m);
  float sum = p;
#pragma unroll
  for (int off = 32; off >= 1; off >>= 1) sum += __shfl_xor(sum, off, 64);
  p /= sum;
  ps[k] = p;
  __syncthreads();
  int half = k >> 5, d = k & 31;
  float acc = 0.f;
#pragma unroll
  for (int j = 0; j < 32; ++j) {
    int kk = half * 32 + j;
    acc += ps[kk] * V[kk * DIMC + h * HDC + d];
  }
  acc += __shfl_xor(acc, 32, 64);
  if (half == 0) O[q * DIMC + h * HDC + d] = acc;
}

__device__ inline float blk_sum128(float v, float* red) {
#pragma unroll
  for (int off = 32; off >= 1; off >>= 1) v += __shfl_xor(v, off, 64);
  if ((threadIdx.x & 63) == 0) red[threadIdx.x >> 6] = v;
  __syncthreads();
  float r = red[0] + red[1];
  __syncthreads();
  return r;
}

__global__ __launch_bounds__(128) void oln_kernel(const float* __restrict__ O0, const float* __restrict__ O1,
                                                  const float* __restrict__ hA, const float* __restrict__ hB,
                                                  const float* __restrict__ Wo, const float* __restrict__ bo,
                                                  const float* __restrict__ g1, const float* __restrict__ be1,
                                                  float* __restrict__ X0, float* __restrict__ X1) {
  __shared__ float os[DIMC];
  __shared__ float red[2];
  int dir = blockIdx.x >> 6, q = blockIdx.x & 63, t = threadIdx.x;
  const float* O = dir ? O1 : O0;
  const float* xq = dir ? hB : hA;
  float* Xo = dir ? X1 : X0;
  os[t] = O[q * DIMC + t];
  __syncthreads();
  float acc = bo[t] + xq[q * DIMC + t];
  for (int k = 0; k < DIMC; ++k) acc += os[k] * Wo[k * DIMC + t];
  float mean = blk_sum128(acc, red) * (1.f / DIMC);
  float d = acc - mean;
  float var = blk_sum128(d * d, red) * (1.f / DIMC);
  Xo[q * DIMC + t] = d * rsqrtf(var + EPSF) * g1[t] + be1[t];
}

__global__ __launch_bounds__(256) void ff1_kernel(const float* __restrict__ X0, const float* __restrict__ X1,
                                                  const float* __restrict__ Wf1, const float* __restrict__ bf1,
                                                  float* __restrict__ F0, float* __restrict__ F1) {
  __shared__ float xs[DIMC];
  int dir = blockIdx.x >> 6, q = blockIdx.x & 63, t = threadIdx.x;
  const float* X = dir ? X1 : X0;
  float* F = dir ? F1 : F0;
  if (t < DIMC) xs[t] = X[q * DIMC + t];
  __syncthreads();
  float acc = bf1[t];
  for (int k = 0; k < DIMC; ++k) acc += xs[k] * Wf1[k * 256 + t];
  acc = (acc > 0.f) ? acc : SLOPEF * acc;
  F[q * 256 + t] = acc;
}

__global__ __launch_bounds__(128) void ffln_kernel(const float* __restrict__ F0, const float* __restrict__ F1,
                                                   const float* __restrict__ X0, const float* __restrict__ X1,
                                                   const float* __restrict__ Wf2, const float* __restrict__ bf2,
                                                   const float* __restrict__ g2, const float* __restrict__ be2,
                                                   float* __restrict__ Y0, float* __restrict__ Y1) {
  __shared__ float fs[256];
  __shared__ float red[2];
  int dir = blockIdx.x >> 6, q = blockIdx.x & 63, t = threadIdx.x;
  const float* F = dir ? F1 : F0;
  const float* X = dir ? X1 : X0;
  float* Y = dir ? Y1 : Y0;
  fs[t] = F[q * 256 + t];
  fs[t + 128] = F[q * 256 + t + 128];
  __syncthreads();
  float acc = bf2[t] + X[q * DIMC + t];
  for (int k = 0; k < 256; ++k) acc += fs[k] * Wf2[k * DIMC + t];
  float mean = blk_sum128(acc, red) * (1.f / DIMC);
  float d = acc - mean;
  float var = blk_sum128(d * d, red) * (1.f / DIMC);
  Y[q * DIMC + t] = d * rsqrtf(var + EPSF) * g2[t] + be2[t];
}

__global__ __launch_bounds__(128) void head_kernel(const float* __restrict__ Y0, const float* __restrict__ Y1,
                                                   const float* __restrict__ Wl1, const float* __restrict__ bl1,
                                                   const float* __restrict__ Wl2, const float* __restrict__ bl2,
                                                   float* __restrict__ out) {
  __shared__ float cs[256];
  __shared__ float red[2];
  int g = blockIdx.x, t = threadIdx.x;
  cs[t] = Y0[g * DIMC + t];
  cs[t + 128] = Y1[g * DIMC + t];
  __syncthreads();
  float acc = bl1[t];
  for (int k = 0; k < 256; ++k) acc += cs[k] * Wl1[k * DIMC + t];
  acc = fmaxf(acc, 0.f);
  float s = blk_sum128(acc * Wl2[t], red);
  if (t == 0) out[g] = s + bl2[0];
}

// ---------------- host ----------------
extern "C" void kernel_launch(void* const* d_in, const int* in_sizes, int n_in,
                              void* d_out, int out_size, void* d_ws, size_t ws_size,
                              hipStream_t stream) {
  const float* xA = (const float*)d_in[0];
  const float* xB = (const float*)d_in[1];
  const int* eiA = (const int*)d_in[2];
  const int* eiB = (const int*)d_in[3];
  const int* batA = (const int*)d_in[4];
  const int* batB = (const int*)d_in[5];
  const float* WA1 = (const float*)d_in[6];
  const float* WA2 = (const float*)d_in[7];
  const float* WB1 = (const float*)d_in[8];
  const float* WB2 = (const float*)d_in[9];
  const float* Wq = (const float*)d_in[10];
  const float* Wk = (const float*)d_in[11];
  const float* Wv = (const float*)d_in[12];
  const float* Wo = (const float*)d_in[13];
  const float* Wf1 = (const float*)d_in[14];
  const float* Wf2 = (const float*)d_in[15];
  const float* Wl1 = (const float*)d_in[16];
  const float* Wl2 = (const float*)d_in[17];
  const float* bA1 = (const float*)d_in[18];
  const float* bA2 = (const float*)d_in[19];
  const float* bB1 = (const float*)d_in[20];
  const float* bB2 = (const float*)d_in[21];
  const float* bq = (const float*)d_in[22];
  const float* bk = (const float*)d_in[23];
  const float* bv = (const float*)d_in[24];
  const float* bo = (const float*)d_in[25];
  const float* bf1 = (const float*)d_in[26];
  const float* bf2 = (const float*)d_in[27];
  const float* bl1 = (const float*)d_in[28];
  const float* bl2 = (const float*)d_in[29];
  const float* g1 = (const float*)d_in[30];
  const float* be1 = (const float*)d_in[31];
  const float* g2 = (const float*)d_in[32];
  const float* be2 = (const float*)d_in[33];

  char* base = (char*)d_ws;
  size_t off = 0;
  auto alloc = [&](size_t bytes) -> char* {
    char* r = base + off;
    off += (bytes + 255) & ~(size_t)255;
    return r;
  };
  unsigned short* h_buf = (unsigned short*)alloc((size_t)2 * N_NODESC * DIMC * 2);   // bf16, both sides
  unsigned short* g_buf = (unsigned short*)alloc((size_t)2 * N_NODESC * DIMC * 2);   // bf16, both sides
  unsigned* packed = (unsigned*)alloc((size_t)2 * N_EDGESC * 4);
  unsigned short* csr16 = (unsigned short*)alloc((size_t)2 * N_EDGESC * 2);
  int* rowptr = (int*)alloc((size_t)2 * (N_NODESC + 1) * 4);
  float* inv = (float*)alloc((size_t)2 * N_NODESC * 4);
  int* hist = (int*)alloc((size_t)2 * KBLK * NBUK * 4);
  int* bbase = (int*)alloc((size_t)2 * KBLK * NBUK * 4);
  int* bucket_base = (int*)alloc((size_t)2 * (NBUK + 1) * 4);
  unsigned short* wtbuf = (unsigned short*)alloc((size_t)4 * 128 * 512 * 2);
  size_t poff0 = off;
  float* psA = (float*)alloc(NGC * DIMC * 4);
  float* psB = (float*)alloc(NGC * DIMC * 4);
  int* pcA = (int*)alloc(NGC * 4);
  int* pcB = (int*)alloc(NGC * 4);
  size_t pbytes = off - poff0;
  float* mhA = (float*)alloc(NGC * DIMC * 4);
  float* mhB = (float*)alloc(NGC * DIMC * 4);
  float* Q0 = (float*)alloc(NGC * DIMC * 4);
  float* K0 = (float*)alloc(NGC * DIMC * 4);
  float* V0 = (float*)alloc(NGC * DIMC * 4);
  float* Q1 = (float*)alloc(NGC * DIMC * 4);
  float* K1 = (float*)alloc(NGC * DIMC * 4);
  float* V1 = (float*)alloc(NGC * DIMC * 4);
  float* O0 = (float*)alloc(NGC * DIMC * 4);
  float* O1 = (float*)alloc(NGC * DIMC * 4);
  float* X0 = (float*)alloc(NGC * DIMC * 4);
  float* X1 = (float*)alloc(NGC * DIMC * 4);
  float* F0 = (float*)alloc(NGC * 256 * 4);
  float* F1 = (float*)alloc(NGC * 256 * 4);
  float* Y0 = (float*)alloc(NGC * DIMC * 4);
  float* Y1 = (float*)alloc(NGC * DIMC * 4);

  hipMemsetAsync(base + poff0, 0, pbytes, stream);
  wconv<<<64, 256, 0, stream>>>(WA1, WA2, WB1, WB2, wtbuf);

  kbhist2<<<2 * KBLK, 1024, 0, stream>>>(eiA, eiB, hist);
  kbscan2<<<2, 1024, 0, stream>>>(hist, bbase, bucket_base);
  kbin2<<<2 * KBLK, 1024, 0, stream>>>(eiA, eiB, bbase, packed);
  kcsr2<<<2 * NBUK, 256, 0, stream>>>(packed, bucket_base, csr16, rowptr, inv);

  gemm_l1<<<2 * GG, 256, 0, stream>>>(xA, xB, wtbuf, inv, h_buf);
  agg12<<<2 * AG, 256, 0, stream>>>(h_buf, inv, rowptr, csr16, bA1, bB1, g_buf, 1);
  gemm_l2<<<2 * GG, 256, 0, stream>>>(g_buf, wtbuf, inv, h_buf);
  agg12<<<2 * AG, 256, 0, stream>>>(h_buf, inv, rowptr, csr16, bA2, bB2, g_buf, 0);
  pool2<<<2 * GG, 128, 0, stream>>>(g_buf, batA, batB, psA, psB, pcA, pcB);

  mean_kernel<<<128, 128, 0, stream>>>(psA, pcA, psB, pcB, mhA, mhB);
  qkv_kernel<<<384, 128, 0, stream>>>(mhA, mhB, Wq, bq, Wk, bk, Wv, bv, Q0, K0, V0, Q1, K1, V1);
  attn_kernel<<<512, 64, 0, stream>>>(Q0, K0, V0, Q1, K1, V1, O0, O1);
  oln_kernel<<<128, 128, 0, stream>>>(O0, O1, mhA, mhB, Wo, bo, g1, be1, X0, X1);
  ff1_kernel<<<128, 256, 0, stream>>>(X0, X1, Wf1, bf1, F0, F1);
  ffln_kernel<<<128, 128, 0, stream>>>(F0, F1, X0, X1, Wf2, bf2, g2, be2, Y0, Y1);
  head_kernel<<<64, 128, 0, stream>>>(Y0, Y1, Wl1, bl1, Wl2, bl2, (float*)d_out);
}

// Round 11
// 268.045 us; speedup vs baseline: 1.7316x; 1.1030x over previous
//
#include <hip/hip_runtime.h>

#define N_NODESC 50000
#define N_EDGESC 800000
#define DIMC 128
#define NGC 64
#define HDC 32
#define SLOPEF 0.01f
#define EPSF 1e-5f
#define SCALEF 0.17677669529663687f  // 32^-0.5

#define NBUK 782   // ceil(50000/64) buckets of 64 dst nodes
#define KBLK 50    // binning blocks per side
#define EPB 16000  // edges per binning block (50*16000 = 800000)
#define GG 782     // gemm/pool blocks per side (64 rows each)
#define AG 12500   // agg blocks per side (4 nodes each)

typedef __attribute__((ext_vector_type(8))) short bf16x8;
typedef __attribute__((ext_vector_type(4))) float f32x4;
typedef __attribute__((ext_vector_type(2))) float f32x2;

// fp32 <-> bf16 (RNE)
static __device__ __forceinline__ unsigned short f2bf(float f) {
  unsigned u = __float_as_uint(f);
  u = u + 0x7FFFu + ((u >> 16) & 1u);
  return (unsigned short)(u >> 16);
}
static __device__ __forceinline__ float bf2f(unsigned short h) {
  return __uint_as_float(((unsigned)h) << 16);
}

// ---- fp8 e4m3 (OCP) pack/unpack: HW cvt if available, manual fallback ----
#if defined(__has_builtin)
#if __has_builtin(__builtin_amdgcn_cvt_pk_f32_fp8) && __has_builtin(__builtin_amdgcn_cvt_pk_fp8_f32)
#define HW_FP8 1
#endif
#endif
#ifndef HW_FP8
#define HW_FP8 0
#endif

static __device__ __forceinline__ unsigned enc_fp8(float x) {
  unsigned u = __float_as_uint(x);
  unsigned s = (u >> 24) & 0x80u;
  unsigned mag = u & 0x7FFFFFFFu;
  if (mag >= 0x43E00000u) return s | 0x7Eu;  // clamp to 448
  unsigned r = mag + 0x7FFFFu + ((mag >> 20) & 1u);  // RNE at bit 20
  int e8 = (int)(r >> 23) - 120;
  if (e8 <= 0) {
    float ax = __uint_as_float(mag);
    int m = (int)(ax * 512.0f + 0.5f);  // denormal: m * 2^-9
    if (m > 7) m = 7;
    return s | (unsigned)m;
  }
  return s | ((unsigned)e8 << 3) | ((r >> 20) & 7u);
}
static __device__ __forceinline__ float dec_fp8(unsigned b) {
  unsigned em = b & 0x7Fu;
  float mag = (em >= 8) ? __uint_as_float((em << 20) + 0x3C000000u)
                        : (float)em * 0.001953125f;  // 2^-9
  return (b & 0x80u) ? -mag : mag;
}
static __device__ __forceinline__ unsigned pk_fp8x4(float a, float b, float c, float d) {
#if HW_FP8
  int v = 0;
  v = __builtin_amdgcn_cvt_pk_fp8_f32(a, b, v, false);
  v = __builtin_amdgcn_cvt_pk_fp8_f32(c, d, v, true);
  return (unsigned)v;
#else
  return enc_fp8(a) | (enc_fp8(b) << 8) | (enc_fp8(c) << 16) | (enc_fp8(d) << 24);
#endif
}
static __device__ __forceinline__ float4 upk_fp8x4(unsigned v) {
#if HW_FP8
  f32x2 lo = __builtin_amdgcn_cvt_pk_f32_fp8((int)v, false);
  f32x2 hi = __builtin_amdgcn_cvt_pk_f32_fp8((int)v, true);
  return make_float4(lo[0], lo[1], hi[0], hi[1]);
#else
  return make_float4(dec_fp8(v & 0xFF), dec_fp8((v >> 8) & 0xFF),
                     dec_fp8((v >> 16) & 0xFF), dec_fp8(v >> 24));
#endif
}

// ---------------- CSR build (both sides per launch) ----------------
__global__ __launch_bounds__(1024) void kbhist2(const int* __restrict__ eiA, const int* __restrict__ eiB,
                                                int* __restrict__ hist) {
  __shared__ int lh[NBUK];
  int side = blockIdx.x / KBLK, blk = blockIdx.x % KBLK;
  const int* ei = side ? eiB : eiA;
  int* hout = hist + side * KBLK * NBUK;
  int t = threadIdx.x;
  for (int i = t; i < NBUK; i += 1024) lh[i] = 0;
  __syncthreads();
  int e0 = blk * EPB;
  for (int e = e0 + t; e < e0 + EPB; e += 1024) {
    int d = ei[N_EDGESC + e];
    atomicAdd(&lh[d >> 6], 1);
  }
  __syncthreads();
  for (int i = t; i < NBUK; i += 1024) hout[blk * NBUK + i] = lh[i];
}

__global__ __launch_bounds__(1024) void kbscan2(const int* __restrict__ hist, int* __restrict__ bbase,
                                                int* __restrict__ bucket_base) {
  __shared__ int sd[1024];
  int side = blockIdx.x;
  const int* h = hist + side * KBLK * NBUK;
  int* bb = bbase + side * KBLK * NBUK;
  int* bub = bucket_base + side * (NBUK + 1);
  int t = threadIdx.x;
  int tot = 0;
  if (t < NBUK) {
    for (int k = 0; k < KBLK; ++k) tot += h[k * NBUK + t];
  }
  sd[t] = tot;
  __syncthreads();
  for (int off = 1; off < 1024; off <<= 1) {
    int u = (t >= off) ? sd[t - off] : 0;
    __syncthreads();
    sd[t] += u;
    __syncthreads();
  }
  if (t < NBUK) {
    int run = sd[t] - tot;  // exclusive bucket base
    bub[t] = run;
    for (int k = 0; k < KBLK; ++k) {
      bb[k * NBUK + t] = run;
      run += h[k * NBUK + t];
    }
  }
  if (t == 0) bub[NBUK] = N_EDGESC;
}

__global__ __launch_bounds__(1024) void kbin2(const int* __restrict__ eiA, const int* __restrict__ eiB,
                                              const int* __restrict__ bbase, unsigned* __restrict__ packed) {
  __shared__ int cur[NBUK];
  int side = blockIdx.x / KBLK, blk = blockIdx.x % KBLK;
  const int* ei = side ? eiB : eiA;
  const int* bb = bbase + side * KBLK * NBUK;
  unsigned* pk = packed + (size_t)side * N_EDGESC;
  int t = threadIdx.x;
  for (int i = t; i < NBUK; i += 1024) cur[i] = bb[blk * NBUK + i];
  __syncthreads();
  int e0 = blk * EPB;
  for (int e = e0 + t; e < e0 + EPB; e += 1024) {
    int s = ei[e];
    int d = ei[N_EDGESC + e];
    int b = d >> 6;
    int pos = atomicAdd(&cur[b], 1);
    pk[pos] = (unsigned)s | ((unsigned)(d & 63) << 16);
  }
}

__global__ __launch_bounds__(256) void kcsr2(const unsigned* __restrict__ packed, const int* __restrict__ bucket_base,
                                             unsigned short* __restrict__ csr16, int* __restrict__ rowptr,
                                             float* __restrict__ inv) {
  __shared__ int h64[64], o64[64], c64[64];
  int side = blockIdx.x / NBUK, b = blockIdx.x % NBUK;
  const unsigned* pk = packed + (size_t)side * N_EDGESC;
  const int* bub = bucket_base + side * (NBUK + 1);
  unsigned short* cs = csr16 + (size_t)side * N_EDGESC;
  int* rp = rowptr + side * (N_NODESC + 1);
  float* iv = inv + side * N_NODESC;
  int t = threadIdx.x;
  int beg = bub[b], end = bub[b + 1];
  if (t < 64) h64[t] = 0;
  __syncthreads();
  for (int e = beg + t; e < end; e += 256) atomicAdd(&h64[pk[e] >> 16], 1);
  __syncthreads();
  if (t == 0) {
    int run = 0;
    for (int j = 0; j < 64; ++j) { o64[j] = run; run += h64[j]; }
  }
  __syncthreads();
  if (t < 64) c64[t] = o64[t];
  __syncthreads();
  for (int e = beg + t; e < end; e += 256) {
    unsigned p = pk[e];
    int pos = atomicAdd(&c64[p >> 16], 1);
    cs[beg + pos] = (unsigned short)(p & 0xFFFFu);
  }
  if (t < 64) {
    int node = b * 64 + t;
    if (node < N_NODESC) {
      rp[node] = beg + o64[t];
      iv[node] = rsqrtf((float)h64[t] + 1.0f);
    }
  }
  if (b == NBUK - 1 && t == 0) rp[N_NODESC] = N_EDGESC;
}

// ---------------- W pre-transform: fragment-major hi/lo bf16 ----------------
__global__ __launch_bounds__(256) void wconv(const float* __restrict__ W0, const float* __restrict__ W1,
                                             const float* __restrict__ W2, const float* __restrict__ W3,
                                             unsigned short* __restrict__ Wt) {
  int m = blockIdx.x >> 4;                              // matrix 0..3
  int idx = (blockIdx.x & 15) * 256 + threadIdx.x;      // 0..4095: (fs,lane)
  int fs = idx >> 6, lane = idx & 63;
  int ks = fs >> 3, nf = fs & 7;
  int n = nf * 16 + (lane & 15);
  int k0 = ks * 32 + (lane >> 4) * 8;
  const float* W = (m == 0) ? W0 : (m == 1) ? W1 : (m == 2) ? W2 : W3;
  unsigned short* hi = Wt + (size_t)m * 128 * 512 + (size_t)(fs * 2) * 512 + lane * 8;
  bf16x8 vh, vl;
#pragma unroll
  for (int j = 0; j < 8; ++j) {
    float a = W[(k0 + j) * DIMC + n];
    unsigned short h = f2bf(a);
    vh[j] = (short)h;
    vl[j] = (short)f2bf(a - bf2f(h));
  }
  *(bf16x8*)hi = vh;
  *(bf16x8*)(hi + 512) = vl;
}

// Shared epilogue: scaled (x16) bf16 in LDS -> fp8 rows (32 uints/row) coalesced-ish.
static __device__ __forceinline__ void epi_store_fp8(const unsigned short* lds, unsigned* Y, int lb) {
  int tr = threadIdx.x >> 2, q = threadIdx.x & 3;
  int grow = lb * 64 + tr;
  if (grow >= N_NODESC) return;
#pragma unroll
  for (int i = 0; i < 8; ++i) {
    int col = (q + 4 * i) * 4;
    ushort4 v = *(const ushort4*)&lds[tr * 136 + col];
    unsigned pk = pk_fp8x4(bf2f(v.x), bf2f(v.y), bf2f(v.z), bf2f(v.w));
    Y[(size_t)grow * 32 + q + 4 * i] = pk;
  }
}

// ---------------- GEMM layer1 (fp32 in): h(fp8, x16) = (X @ W1) * inv * 16 ----------------
__global__ __launch_bounds__(256) void gemm_l1(const float* __restrict__ xA, const float* __restrict__ xB,
                                               const unsigned short* __restrict__ Wt, const float* __restrict__ inv,
                                               unsigned* __restrict__ H) {
  __shared__ unsigned short lds[64 * 136];
  int side = blockIdx.x / GG, lb = blockIdx.x % GG;
  const float* X = side ? xB : xA;
  const unsigned short* Wm = Wt + (size_t)(side * 2) * 128 * 512;
  const float* iv = inv + side * N_NODESC;
  unsigned* Y = H + (size_t)side * N_NODESC * 32;
  int wave = threadIdx.x >> 6, lane = threadIdx.x & 63;
  int l15 = lane & 15, kb = lane >> 4;
  int row0 = lb * 64 + wave * 16;
  int rA = row0 + l15;
  const bool valid = rA < N_NODESC;
  f32x4 acc[8];
#pragma unroll
  for (int nf = 0; nf < 8; ++nf) acc[nf] = 0.f;
#pragma unroll
  for (int ks = 0; ks < 4; ++ks) {
    int kbase = ks * 32 + kb * 8;
    bf16x8 a;
    if (valid) {
      const float* xp = &X[(size_t)rA * DIMC + kbase];
      float4 x0 = *(const float4*)xp;
      float4 x1 = *(const float4*)(xp + 4);
      a[0] = (short)f2bf(x0.x); a[1] = (short)f2bf(x0.y);
      a[2] = (short)f2bf(x0.z); a[3] = (short)f2bf(x0.w);
      a[4] = (short)f2bf(x1.x); a[5] = (short)f2bf(x1.y);
      a[6] = (short)f2bf(x1.z); a[7] = (short)f2bf(x1.w);
    } else {
      a = (short)0;
    }
    const unsigned short* wp = Wm + (size_t)(ks * 16) * 512 + lane * 8;
#pragma unroll
    for (int nf = 0; nf < 8; ++nf) {
      bf16x8 bh = *(const bf16x8*)(wp + (nf * 2) * 512);
      bf16x8 bl = *(const bf16x8*)(wp + (nf * 2 + 1) * 512);
      acc[nf] = __builtin_amdgcn_mfma_f32_16x16x32_bf16(a, bh, acc[nf], 0, 0, 0);
      acc[nf] = __builtin_amdgcn_mfma_f32_16x16x32_bf16(a, bl, acc[nf], 0, 0, 0);
    }
  }
  int lrow = wave * 16 + kb * 4;
#pragma unroll
  for (int r = 0; r < 4; ++r) {
    int rr = row0 + kb * 4 + r;
    float s = (rr < N_NODESC) ? iv[rr] * 16.0f : 0.f;  // x16 into fp8 range
#pragma unroll
    for (int nf = 0; nf < 8; ++nf) {
      lds[(lrow + r) * 136 + nf * 16 + l15] = f2bf(acc[nf][r] * s);
    }
  }
  __syncthreads();
  epi_store_fp8(lds, Y, lb);
}

// ---------------- GEMM layer2 (bf16 in): h(fp8, x16) = (G @ W2) * inv * 16 ----------------
__global__ __launch_bounds__(256) void gemm_l2(const unsigned short* __restrict__ Gb,
                                               const unsigned short* __restrict__ Wt, const float* __restrict__ inv,
                                               unsigned* __restrict__ H) {
  __shared__ unsigned short lds[64 * 136];
  int side = blockIdx.x / GG, lb = blockIdx.x % GG;
  const unsigned short* X = Gb + (size_t)side * N_NODESC * DIMC;
  const unsigned short* Wm = Wt + (size_t)(side * 2 + 1) * 128 * 512;
  const float* iv = inv + side * N_NODESC;
  unsigned* Y = H + (size_t)side * N_NODESC * 32;
  int wave = threadIdx.x >> 6, lane = threadIdx.x & 63;
  int l15 = lane & 15, kb = lane >> 4;
  int row0 = lb * 64 + wave * 16;
  int rA = row0 + l15;
  const bool valid = rA < N_NODESC;
  f32x4 acc[8];
#pragma unroll
  for (int nf = 0; nf < 8; ++nf) acc[nf] = 0.f;
#pragma unroll
  for (int ks = 0; ks < 4; ++ks) {
    int kbase = ks * 32 + kb * 8;
    bf16x8 a;
    if (valid) {
      a = *(const bf16x8*)&X[(size_t)rA * DIMC + kbase];
    } else {
      a = (short)0;
    }
    const unsigned short* wp = Wm + (size_t)(ks * 16) * 512 + lane * 8;
#pragma unroll
    for (int nf = 0; nf < 8; ++nf) {
      bf16x8 bh = *(const bf16x8*)(wp + (nf * 2) * 512);
      bf16x8 bl = *(const bf16x8*)(wp + (nf * 2 + 1) * 512);
      acc[nf] = __builtin_amdgcn_mfma_f32_16x16x32_bf16(a, bh, acc[nf], 0, 0, 0);
      acc[nf] = __builtin_amdgcn_mfma_f32_16x16x32_bf16(a, bl, acc[nf], 0, 0, 0);
    }
  }
  int lrow = wave * 16 + kb * 4;
#pragma unroll
  for (int r = 0; r < 4; ++r) {
    int rr = row0 + kb * 4 + r;
    float s = (rr < N_NODESC) ? iv[rr] * 16.0f : 0.f;
#pragma unroll
    for (int nf = 0; nf < 8; ++nf) {
      lds[(lrow + r) * 136 + nf * 16 + l15] = f2bf(acc[nf][r] * s);
    }
  }
  __syncthreads();
  epi_store_fp8(lds, Y, lb);
}

// ---------------- aggregation (both sides, fp8 gather): g(bf16) ----------------
__global__ __launch_bounds__(256) void agg12(const unsigned* __restrict__ H, const float* __restrict__ inv,
                                             const int* __restrict__ rowptr, const unsigned short* __restrict__ csr16,
                                             const float* __restrict__ biasA, const float* __restrict__ biasB,
                                             unsigned short* __restrict__ G, int do_relu) {
  int side = blockIdx.x / AG, lb = blockIdx.x % AG;
  int node = lb * 4 + (threadIdx.x >> 6);
  if (node >= N_NODESC) return;
  const unsigned* Hp = H + (size_t)side * N_NODESC * 32;
  const float* iv = inv + side * N_NODESC;
  const int* rp = rowptr + side * (N_NODESC + 1);
  const unsigned short* csr = csr16 + (size_t)side * N_EDGESC;
  const float* bias = side ? biasB : biasA;
  unsigned short* out = G + (size_t)side * N_NODESC * DIMC;
  int lane = threadIdx.x & 63;
  int ug = lane & 31;           // uint index within row (4 cols)
  int slot = lane >> 5;
  int beg = rp[node], end = rp[node + 1];
  float4 acc = make_float4(0.f, 0.f, 0.f, 0.f);
  int e = beg;
  for (; e + 8 <= end; e += 8) {
    int s0 = csr[e + slot];
    int s1 = csr[e + 2 + slot];
    int s2 = csr[e + 4 + slot];
    int s3 = csr[e + 6 + slot];
    unsigned u0 = Hp[(size_t)s0 * 32 + ug];
    unsigned u1 = Hp[(size_t)s1 * 32 + ug];
    unsigned u2 = Hp[(size_t)s2 * 32 + ug];
    unsigned u3 = Hp[(size_t)s3 * 32 + ug];
    float4 v0 = upk_fp8x4(u0);
    float4 v1 = upk_fp8x4(u1);
    float4 v2 = upk_fp8x4(u2);
    float4 v3 = upk_fp8x4(u3);
    acc.x += (v0.x + v1.x) + (v2.x + v3.x);
    acc.y += (v0.y + v1.y) + (v2.y + v3.y);
    acc.z += (v0.z + v1.z) + (v2.z + v3.z);
    acc.w += (v0.w + v1.w) + (v2.w + v3.w);
  }
  for (int t = e + slot; t < end; t += 2) {
    int s = csr[t];
    float4 v = upk_fp8x4(Hp[(size_t)s * 32 + ug]);
    acc.x += v.x; acc.y += v.y; acc.z += v.z; acc.w += v.w;
  }
  acc.x += __shfl_xor(acc.x, 32, 64);
  acc.y += __shfl_xor(acc.y, 32, 64);
  acc.z += __shfl_xor(acc.z, 32, 64);
  acc.w += __shfl_xor(acc.w, 32, 64);
  if (slot == 0) {
    float4 sv = upk_fp8x4(Hp[(size_t)node * 32 + ug]);
    float sc = iv[node] * 0.0625f;  // undo x16
    const float* bp = &bias[ug * 4];
    float4 b = *(const float4*)bp;
    float4 o;
    o.x = (acc.x + sv.x) * sc + b.x;
    o.y = (acc.y + sv.y) * sc + b.y;
    o.z = (acc.z + sv.z) * sc + b.z;
    o.w = (acc.w + sv.w) * sc + b.w;
    if (do_relu) {
      o.x = (o.x > 0.f) ? o.x : SLOPEF * o.x;
      o.y = (o.y > 0.f) ? o.y : SLOPEF * o.y;
      o.z = (o.z > 0.f) ? o.z : SLOPEF * o.z;
      o.w = (o.w > 0.f) ? o.w : SLOPEF * o.w;
    }
    ushort4 ob;
    ob.x = f2bf(o.x); ob.y = f2bf(o.y); ob.z = f2bf(o.z); ob.w = f2bf(o.w);
    *(ushort4*)&out[(size_t)node * DIMC + ug * 4] = ob;
  }
}

// ---------------- pooling (both sides, bf16 in) ----------------
__global__ __launch_bounds__(128) void pool2(const unsigned short* __restrict__ G,
                                             const int* __restrict__ batA, const int* __restrict__ batB,
                                             float* __restrict__ psA, float* __restrict__ psB,
                                             int* __restrict__ pcA, int* __restrict__ pcB) {
  int side = blockIdx.x / GG, lb = blockIdx.x % GG;
  const unsigned short* g = G + (size_t)side * N_NODESC * DIMC;
  const int* batch = side ? batB : batA;
  float* psum = side ? psB : psA;
  int* pcnt = side ? pcB : pcA;
  int t = threadIdx.x;
  int n0 = lb * 64;
  int nend = min(n0 + 64, N_NODESC);
  int cur = batch[n0];
  float acc = 0.f;
  int c = 0;
  for (int n = n0; n < nend; ++n) {
    int b = batch[n];
    if (b != cur) {
      atomicAdd(&psum[cur * DIMC + t], acc);
      if (t == 0) atomicAdd(&pcnt[cur], c);
      acc = 0.f;
      c = 0;
      cur = b;
    }
    acc += bf2f(g[(size_t)n * DIMC + t]);
    c += 1;
  }
  atomicAdd(&psum[cur * DIMC + t], acc);
  if (t == 0) atomicAdd(&pcnt[cur], c);
}

__global__ __launch_bounds__(128) void mean_kernel(const float* __restrict__ psA, const int* __restrict__ pcA,
                                                   const float* __restrict__ psB, const int* __restrict__ pcB,
                                                   float* __restrict__ hA, float* __restrict__ hB) {
  int dir = blockIdx.x >> 6, g = blockIdx.x & 63, t = threadIdx.x;
  const float* ps = dir ? psB : psA;
  const int* pc = dir ? pcB : pcA;
  float* h = dir ? hB : hA;
  h[g * DIMC + t] = ps[g * DIMC + t] / (float)max(pc[g], 1);
}

// ---------------- attention (64 tokens per side) ----------------
__global__ __launch_bounds__(128) void qkv_kernel(const float* __restrict__ hA, const float* __restrict__ hB,
                                                  const float* __restrict__ Wq, const float* __restrict__ bq,
                                                  const float* __restrict__ Wk, const float* __restrict__ bk,
                                                  const float* __restrict__ Wv, const float* __restrict__ bv,
                                                  float* __restrict__ Q0, float* __restrict__ K0, float* __restrict__ V0,
                                                  float* __restrict__ Q1, float* __restrict__ K1, float* __restrict__ V1) {
  __shared__ float xs[DIMC];
  int task = blockIdx.x >> 6, r = blockIdx.x & 63, t = threadIdx.x;
  const float *X, *W, *b;
  float* Y;
  switch (task) {
    case 0: X = hA; W = Wq; b = bq; Y = Q0; break;
    case 1: X = hB; W = Wk; b = bk; Y = K0; break;
    case 2: X = hB; W = Wv; b = bv; Y = V0; break;
    case 3: X = hB; W = Wq; b = bq; Y = Q1; break;
    case 4: X = hA; W = Wk; b = bk; Y = K1; break;
    default: X = hA; W = Wv; b = bv; Y = V1; break;
  }
  xs[t] = X[r * DIMC + t];
  __syncthreads();
  float acc = b[t];
  for (int k = 0; k < DIMC; ++k) acc += xs[k] * W[k * DIMC + t];
  Y[r * DIMC + t] = acc;
}

__global__ __launch_bounds__(64) void attn_kernel(const float* __restrict__ Q0, const float* __restrict__ K0,
                                                  const float* __restrict__ V0, const float* __restrict__ Q1,
                                                  const float* __restrict__ K1, const float* __restrict__ V1,
                                                  float* __restrict__ O0, float* __restrict__ O1) {
  __shared__ float ps[64];
  int b = blockIdx.x;
  int dir = b >> 8, h = (b >> 6) & 3, q = b & 63;
  const float* Q = dir ? Q1 : Q0;
  const float* K = dir ? K1 : K0;
  const float* V = dir ? V1 : V0;
  float* O = dir ? O1 : O0;
  int k = threadIdx.x;
  const float* qp = Q + q * DIMC + h * HDC;
  const float* kp = K + k * DIMC + h * HDC;
  float s = 0.f;
#pragma unroll
  for (int d = 0; d < HDC; ++d) s += qp[d] * kp[d];
  s *= SCALEF;
  float m = s;
#pragma unroll
  for (int off = 32; off >= 1; off >>= 1) m = fmaxf(m, __shfl_xor(m, off, 64));
  float p = __expf(s - m);
  float sum = p;
#pragma unroll
  for (int off = 32; off >= 1; off >>= 1) sum += __shfl_xor(sum, off, 64);
  p /= sum;
  ps[k] = p;
  __syncthreads();
  int half = k >> 5, d = k & 31;
  float acc = 0.f;
#pragma unroll
  for (int j = 0; j < 32; ++j) {
    int kk = half * 32 + j;
    acc += ps[kk] * V[kk * DIMC + h * HDC + d];
  }
  acc += __shfl_xor(acc, 32, 64);
  if (half == 0) O[q * DIMC + h * HDC + d] = acc;
}

__device__ inline float blk_sum128(float v, float* red) {
#pragma unroll
  for (int off = 32; off >= 1; off >>= 1) v += __shfl_xor(v, off, 64);
  if ((threadIdx.x & 63) == 0) red[threadIdx.x >> 6] = v;
  __syncthreads();
  float r = red[0] + red[1];
  __syncthreads();
  return r;
}

__global__ __launch_bounds__(128) void oln_kernel(const float* __restrict__ O0, const float* __restrict__ O1,
                                                  const float* __restrict__ hA, const float* __restrict__ hB,
                                                  const float* __restrict__ Wo, const float* __restrict__ bo,
                                                  const float* __restrict__ g1, const float* __restrict__ be1,
                                                  float* __restrict__ X0, float* __restrict__ X1) {
  __shared__ float os[DIMC];
  __shared__ float red[2];
  int dir = blockIdx.x >> 6, q = blockIdx.x & 63, t = threadIdx.x;
  const float* O = dir ? O1 : O0;
  const float* xq = dir ? hB : hA;
  float* Xo = dir ? X1 : X0;
  os[t] = O[q * DIMC + t];
  __syncthreads();
  float acc = bo[t] + xq[q * DIMC + t];
  for (int k = 0; k < DIMC; ++k) acc += os[k] * Wo[k * DIMC + t];
  float mean = blk_sum128(acc, red) * (1.f / DIMC);
  float d = acc - mean;
  float var = blk_sum128(d * d, red) * (1.f / DIMC);
  Xo[q * DIMC + t] = d * rsqrtf(var + EPSF) * g1[t] + be1[t];
}

__global__ __launch_bounds__(256) void ff1_kernel(const float* __restrict__ X0, const float* __restrict__ X1,
                                                  const float* __restrict__ Wf1, const float* __restrict__ bf1,
                                                  float* __restrict__ F0, float* __restrict__ F1) {
  __shared__ float xs[DIMC];
  int dir = blockIdx.x >> 6, q = blockIdx.x & 63, t = threadIdx.x;
  const float* X = dir ? X1 : X0;
  float* F = dir ? F1 : F0;
  if (t < DIMC) xs[t] = X[q * DIMC + t];
  __syncthreads();
  float acc = bf1[t];
  for (int k = 0; k < DIMC; ++k) acc += xs[k] * Wf1[k * 256 + t];
  acc = (acc > 0.f) ? acc : SLOPEF * acc;
  F[q * 256 + t] = acc;
}

__global__ __launch_bounds__(128) void ffln_kernel(const float* __restrict__ F0, const float* __restrict__ F1,
                                                   const float* __restrict__ X0, const float* __restrict__ X1,
                                                   const float* __restrict__ Wf2, const float* __restrict__ bf2,
                                                   const float* __restrict__ g2, const float* __restrict__ be2,
                                                   float* __restrict__ Y0, float* __restrict__ Y1) {
  __shared__ float fs[256];
  __shared__ float red[2];
  int dir = blockIdx.x >> 6, q = blockIdx.x & 63, t = threadIdx.x;
  const float* F = dir ? F1 : F0;
  const float* X = dir ? X1 : X0;
  float* Y = dir ? Y1 : Y0;
  fs[t] = F[q * 256 + t];
  fs[t + 128] = F[q * 256 + t + 128];
  __syncthreads();
  float acc = bf2[t] + X[q * DIMC + t];
  for (int k = 0; k < 256; ++k) acc += fs[k] * Wf2[k * DIMC + t];
  float mean = blk_sum128(acc, red) * (1.f / DIMC);
  float d = acc - mean;
  float var = blk_sum128(d * d, red) * (1.f / DIMC);
  Y[q * DIMC + t] = d * rsqrtf(var + EPSF) * g2[t] + be2[t];
}

__global__ __launch_bounds__(128) void head_kernel(const float* __restrict__ Y0, const float* __restrict__ Y1,
                                                   const float* __restrict__ Wl1, const float* __restrict__ bl1,
                                                   const float* __restrict__ Wl2, const float* __restrict__ bl2,
                                                   float* __restrict__ out) {
  __shared__ float cs[256];
  __shared__ float red[2];
  int g = blockIdx.x, t = threadIdx.x;
  cs[t] = Y0[g * DIMC + t];
  cs[t + 128] = Y1[g * DIMC + t];
  __syncthreads();
  float acc = bl1[t];
  for (int k = 0; k < 256; ++k) acc += cs[k] * Wl1[k * DIMC + t];
  acc = fmaxf(acc, 0.f);
  float s = blk_sum128(acc * Wl2[t], red);
  if (t == 0) out[g] = s + bl2[0];
}

// ---------------- host ----------------
extern "C" void kernel_launch(void* const* d_in, const int* in_sizes, int n_in,
                              void* d_out, int out_size, void* d_ws, size_t ws_size,
                              hipStream_t stream) {
  const float* xA = (const float*)d_in[0];
  const float* xB = (const float*)d_in[1];
  const int* eiA = (const int*)d_in[2];
  const int* eiB = (const int*)d_in[3];
  const int* batA = (const int*)d_in[4];
  const int* batB = (const int*)d_in[5];
  const float* WA1 = (const float*)d_in[6];
  const float* WA2 = (const float*)d_in[7];
  const float* WB1 = (const float*)d_in[8];
  const float* WB2 = (const float*)d_in[9];
  const float* Wq = (const float*)d_in[10];
  const float* Wk = (const float*)d_in[11];
  const float* Wv = (const float*)d_in[12];
  const float* Wo = (const float*)d_in[13];
  const float* Wf1 = (const float*)d_in[14];
  const float* Wf2 = (const float*)d_in[15];
  const float* Wl1 = (const float*)d_in[16];
  const float* Wl2 = (const float*)d_in[17];
  const float* bA1 = (const float*)d_in[18];
  const float* bA2 = (const float*)d_in[19];
  const float* bB1 = (const float*)d_in[20];
  const float* bB2 = (const float*)d_in[21];
  const float* bq = (const float*)d_in[22];
  const float* bk = (const float*)d_in[23];
  const float* bv = (const float*)d_in[24];
  const float* bo = (const float*)d_in[25];
  const float* bf1 = (const float*)d_in[26];
  const float* bf2 = (const float*)d_in[27];
  const float* bl1 = (const float*)d_in[28];
  const float* bl2 = (const float*)d_in[29];
  const float* g1 = (const float*)d_in[30];
  const float* be1 = (const float*)d_in[31];
  const float* g2 = (const float*)d_in[32];
  const float* be2 = (const float*)d_in[33];

  char* base = (char*)d_ws;
  size_t off = 0;
  auto alloc = [&](size_t bytes) -> char* {
    char* r = base + off;
    off += (bytes + 255) & ~(size_t)255;
    return r;
  };
  unsigned* h_buf = (unsigned*)alloc((size_t)2 * N_NODESC * 32 * 4);                // fp8 x16, both sides
  unsigned short* g_buf = (unsigned short*)alloc((size_t)2 * N_NODESC * DIMC * 2);  // bf16, both sides
  unsigned* packed = (unsigned*)alloc((size_t)2 * N_EDGESC * 4);
  unsigned short* csr16 = (unsigned short*)alloc((size_t)2 * N_EDGESC * 2);
  int* rowptr = (int*)alloc((size_t)2 * (N_NODESC + 1) * 4);
  float* inv = (float*)alloc((size_t)2 * N_NODESC * 4);
  int* hist = (int*)alloc((size_t)2 * KBLK * NBUK * 4);
  int* bbase = (int*)alloc((size_t)2 * KBLK * NBUK * 4);
  int* bucket_base = (int*)alloc((size_t)2 * (NBUK + 1) * 4);
  unsigned short* wtbuf = (unsigned short*)alloc((size_t)4 * 128 * 512 * 2);
  size_t poff0 = off;
  float* psA = (float*)alloc(NGC * DIMC * 4);
  float* psB = (float*)alloc(NGC * DIMC * 4);
  int* pcA = (int*)alloc(NGC * 4);
  int* pcB = (int*)alloc(NGC * 4);
  size_t pbytes = off - poff0;
  float* mhA = (float*)alloc(NGC * DIMC * 4);
  float* mhB = (float*)alloc(NGC * DIMC * 4);
  float* Q0 = (float*)alloc(NGC * DIMC * 4);
  float* K0 = (float*)alloc(NGC * DIMC * 4);
  float* V0 = (float*)alloc(NGC * DIMC * 4);
  float* Q1 = (float*)alloc(NGC * DIMC * 4);
  float* K1 = (float*)alloc(NGC * DIMC * 4);
  float* V1 = (float*)alloc(NGC * DIMC * 4);
  float* O0 = (float*)alloc(NGC * DIMC * 4);
  float* O1 = (float*)alloc(NGC * DIMC * 4);
  float* X0 = (float*)alloc(NGC * DIMC * 4);
  float* X1 = (float*)alloc(NGC * DIMC * 4);
  float* F0 = (float*)alloc(NGC * 256 * 4);
  float* F1 = (float*)alloc(NGC * 256 * 4);
  float* Y0 = (float*)alloc(NGC * DIMC * 4);
  float* Y1 = (float*)alloc(NGC * DIMC * 4);

  hipMemsetAsync(base + poff0, 0, pbytes, stream);
  wconv<<<64, 256, 0, stream>>>(WA1, WA2, WB1, WB2, wtbuf);

  kbhist2<<<2 * KBLK, 1024, 0, stream>>>(eiA, eiB, hist);
  kbscan2<<<2, 1024, 0, stream>>>(hist, bbase, bucket_base);
  kbin2<<<2 * KBLK, 1024, 0, stream>>>(eiA, eiB, bbase, packed);
  kcsr2<<<2 * NBUK, 256, 0, stream>>>(packed, bucket_base, csr16, rowptr, inv);

  gemm_l1<<<2 * GG, 256, 0, stream>>>(xA, xB, wtbuf, inv, h_buf);
  agg12<<<2 * AG, 256, 0, stream>>>(h_buf, inv, rowptr, csr16, bA1, bB1, g_buf, 1);
  gemm_l2<<<2 * GG, 256, 0, stream>>>(g_buf, wtbuf, inv, h_buf);
  agg12<<<2 * AG, 256, 0, stream>>>(h_buf, inv, rowptr, csr16, bA2, bB2, g_buf, 0);
  pool2<<<2 * GG, 128, 0, stream>>>(g_buf, batA, batB, psA, psB, pcA, pcB);

  mean_kernel<<<128, 128, 0, stream>>>(psA, pcA, psB, pcB, mhA, mhB);
  qkv_kernel<<<384, 128, 0, stream>>>(mhA, mhB, Wq, bq, Wk, bk, Wv, bv, Q0, K0, V0, Q1, K1, V1);
  attn_kernel<<<512, 64, 0, stream>>>(Q0, K0, V0, Q1, K1, V1, O0, O1);
  oln_kernel<<<128, 128, 0, stream>>>(O0, O1, mhA, mhB, Wo, bo, g1, be1, X0, X1);
  ff1_kernel<<<128, 256, 0, stream>>>(X0, X1, Wf1, bf1, F0, F1);
  ffln_kernel<<<128, 128, 0, stream>>>(F0, F1, X0, X1, Wf2, bf2, g2, be2, Y0, Y1);
  head_kernel<<<64, 128, 0, stream>>>(Y0, Y1, Wl1, bl1, Wl2, bl2, (float*)d_out);
}

// Round 12
// 262.512 us; speedup vs baseline: 1.7681x; 1.0211x over previous
//
#include <hip/hip_runtime.h>

#define N_NODESC 50000
#define N_EDGESC 800000
#define DIMC 128
#define NGC 64
#define HDC 32
#define SLOPEF 0.01f
#define EPSF 1e-5f
#define SCALEF 0.17677669529663687f  // 32^-0.5

#define NBUK 782   // ceil(50000/64) buckets of 64 dst nodes
#define KBLK 50    // binning blocks per side
#define EPB 16000  // edges per binning block (50*16000 = 800000)
#define GG 782     // gemm/pool blocks per side (64 rows each)
#define AG 12500   // agg blocks per side (4 nodes each)

typedef __attribute__((ext_vector_type(8))) short bf16x8;
typedef __attribute__((ext_vector_type(4))) float f32x4;
typedef __attribute__((ext_vector_type(2))) float f32x2;

// fp32 <-> bf16 (RNE)
static __device__ __forceinline__ unsigned short f2bf(float f) {
  unsigned u = __float_as_uint(f);
  u = u + 0x7FFFu + ((u >> 16) & 1u);
  return (unsigned short)(u >> 16);
}
static __device__ __forceinline__ float bf2f(unsigned short h) {
  return __uint_as_float(((unsigned)h) << 16);
}

// ---- fp8 e4m3 (OCP) pack/unpack: HW cvt if available, manual fallback ----
#if defined(__has_builtin)
#if __has_builtin(__builtin_amdgcn_cvt_pk_f32_fp8) && __has_builtin(__builtin_amdgcn_cvt_pk_fp8_f32)
#define HW_FP8 1
#endif
#endif
#ifndef HW_FP8
#define HW_FP8 0
#endif

static __device__ __forceinline__ unsigned enc_fp8(float x) {
  unsigned u = __float_as_uint(x);
  unsigned s = (u >> 24) & 0x80u;
  unsigned mag = u & 0x7FFFFFFFu;
  if (mag >= 0x43E00000u) return s | 0x7Eu;  // clamp to 448
  unsigned r = mag + 0x7FFFFu + ((mag >> 20) & 1u);  // RNE at bit 20
  int e8 = (int)(r >> 23) - 120;
  if (e8 <= 0) {
    float ax = __uint_as_float(mag);
    int m = (int)(ax * 512.0f + 0.5f);  // denormal: m * 2^-9
    if (m > 7) m = 7;
    return s | (unsigned)m;
  }
  return s | ((unsigned)e8 << 3) | ((r >> 20) & 7u);
}
static __device__ __forceinline__ float dec_fp8(unsigned b) {
  unsigned em = b & 0x7Fu;
  float mag = (em >= 8) ? __uint_as_float((em << 20) + 0x3C000000u)
                        : (float)em * 0.001953125f;  // 2^-9
  return (b & 0x80u) ? -mag : mag;
}
static __device__ __forceinline__ unsigned pk_fp8x4(float a, float b, float c, float d) {
#if HW_FP8
  int v = 0;
  v = __builtin_amdgcn_cvt_pk_fp8_f32(a, b, v, false);
  v = __builtin_amdgcn_cvt_pk_fp8_f32(c, d, v, true);
  return (unsigned)v;
#else
  return enc_fp8(a) | (enc_fp8(b) << 8) | (enc_fp8(c) << 16) | (enc_fp8(d) << 24);
#endif
}
static __device__ __forceinline__ float4 upk_fp8x4(unsigned v) {
#if HW_FP8
  f32x2 lo = __builtin_amdgcn_cvt_pk_f32_fp8((int)v, false);
  f32x2 hi = __builtin_amdgcn_cvt_pk_f32_fp8((int)v, true);
  return make_float4(lo[0], lo[1], hi[0], hi[1]);
#else
  return make_float4(dec_fp8(v & 0xFF), dec_fp8((v >> 8) & 0xFF),
                     dec_fp8((v >> 16) & 0xFF), dec_fp8(v >> 24));
#endif
}

// ---------------- CSR build (both sides per launch) ----------------
__global__ __launch_bounds__(1024) void kbhist2(const int* __restrict__ eiA, const int* __restrict__ eiB,
                                                int* __restrict__ hist) {
  __shared__ int lh[NBUK];
  int side = blockIdx.x / KBLK, blk = blockIdx.x % KBLK;
  const int* ei = side ? eiB : eiA;
  int* hout = hist + side * KBLK * NBUK;
  int t = threadIdx.x;
  for (int i = t; i < NBUK; i += 1024) lh[i] = 0;
  __syncthreads();
  int e0 = blk * EPB;
  for (int e = e0 + t; e < e0 + EPB; e += 1024) {
    int d = ei[N_EDGESC + e];
    atomicAdd(&lh[d >> 6], 1);
  }
  __syncthreads();
  for (int i = t; i < NBUK; i += 1024) hout[blk * NBUK + i] = lh[i];
}

__global__ __launch_bounds__(1024) void kbscan2(const int* __restrict__ hist, int* __restrict__ bbase,
                                                int* __restrict__ bucket_base) {
  __shared__ int sd[1024];
  int side = blockIdx.x;
  const int* h = hist + side * KBLK * NBUK;
  int* bb = bbase + side * KBLK * NBUK;
  int* bub = bucket_base + side * (NBUK + 1);
  int t = threadIdx.x;
  int tot = 0;
  if (t < NBUK) {
    for (int k = 0; k < KBLK; ++k) tot += h[k * NBUK + t];
  }
  sd[t] = tot;
  __syncthreads();
  for (int off = 1; off < 1024; off <<= 1) {
    int u = (t >= off) ? sd[t - off] : 0;
    __syncthreads();
    sd[t] += u;
    __syncthreads();
  }
  if (t < NBUK) {
    int run = sd[t] - tot;  // exclusive bucket base
    bub[t] = run;
    for (int k = 0; k < KBLK; ++k) {
      bb[k * NBUK + t] = run;
      run += h[k * NBUK + t];
    }
  }
  if (t == 0) bub[NBUK] = N_EDGESC;
}

__global__ __launch_bounds__(1024) void kbin2(const int* __restrict__ eiA, const int* __restrict__ eiB,
                                              const int* __restrict__ bbase, unsigned* __restrict__ packed) {
  __shared__ int cur[NBUK];
  int side = blockIdx.x / KBLK, blk = blockIdx.x % KBLK;
  const int* ei = side ? eiB : eiA;
  const int* bb = bbase + side * KBLK * NBUK;
  unsigned* pk = packed + (size_t)side * N_EDGESC;
  int t = threadIdx.x;
  for (int i = t; i < NBUK; i += 1024) cur[i] = bb[blk * NBUK + i];
  __syncthreads();
  int e0 = blk * EPB;
  for (int e = e0 + t; e < e0 + EPB; e += 1024) {
    int s = ei[e];
    int d = ei[N_EDGESC + e];
    int b = d >> 6;
    int pos = atomicAdd(&cur[b], 1);
    pk[pos] = (unsigned)s | ((unsigned)(d & 63) << 16);
  }
}

__global__ __launch_bounds__(256) void kcsr2(const unsigned* __restrict__ packed, const int* __restrict__ bucket_base,
                                             unsigned short* __restrict__ csr16, int* __restrict__ rowptr,
                                             float* __restrict__ inv) {
  __shared__ int h64[64], o64[64], c64[64];
  int side = blockIdx.x / NBUK, b = blockIdx.x % NBUK;
  const unsigned* pk = packed + (size_t)side * N_EDGESC;
  const int* bub = bucket_base + side * (NBUK + 1);
  unsigned short* cs = csr16 + (size_t)side * N_EDGESC;
  int* rp = rowptr + side * (N_NODESC + 1);
  float* iv = inv + side * N_NODESC;
  int t = threadIdx.x;
  int beg = bub[b], end = bub[b + 1];
  if (t < 64) h64[t] = 0;
  __syncthreads();
  for (int e = beg + t; e < end; e += 256) atomicAdd(&h64[pk[e] >> 16], 1);
  __syncthreads();
  if (t == 0) {
    int run = 0;
    for (int j = 0; j < 64; ++j) { o64[j] = run; run += h64[j]; }
  }
  __syncthreads();
  if (t < 64) c64[t] = o64[t];
  __syncthreads();
  for (int e = beg + t; e < end; e += 256) {
    unsigned p = pk[e];
    int pos = atomicAdd(&c64[p >> 16], 1);
    cs[beg + pos] = (unsigned short)(p & 0xFFFFu);
  }
  if (t < 64) {
    int node = b * 64 + t;
    if (node < N_NODESC) {
      rp[node] = beg + o64[t];
      iv[node] = rsqrtf((float)h64[t] + 1.0f);
    }
  }
  if (b == NBUK - 1 && t == 0) rp[N_NODESC] = N_EDGESC;
}

// ---------------- W pre-transform: fragment-major hi/lo bf16 ----------------
__global__ __launch_bounds__(256) void wconv(const float* __restrict__ W0, const float* __restrict__ W1,
                                             const float* __restrict__ W2, const float* __restrict__ W3,
                                             unsigned short* __restrict__ Wt) {
  int m = blockIdx.x >> 4;                              // matrix 0..3
  int idx = (blockIdx.x & 15) * 256 + threadIdx.x;      // 0..4095: (fs,lane)
  int fs = idx >> 6, lane = idx & 63;
  int ks = fs >> 3, nf = fs & 7;
  int n = nf * 16 + (lane & 15);
  int k0 = ks * 32 + (lane >> 4) * 8;
  const float* W = (m == 0) ? W0 : (m == 1) ? W1 : (m == 2) ? W2 : W3;
  unsigned short* hi = Wt + (size_t)m * 128 * 512 + (size_t)(fs * 2) * 512 + lane * 8;
  bf16x8 vh, vl;
#pragma unroll
  for (int j = 0; j < 8; ++j) {
    float a = W[(k0 + j) * DIMC + n];
    unsigned short h = f2bf(a);
    vh[j] = (short)h;
    vl[j] = (short)f2bf(a - bf2f(h));
  }
  *(bf16x8*)hi = vh;
  *(bf16x8*)(hi + 512) = vl;
}

// Shared epilogue: scaled (x16) bf16 in LDS -> fp8 rows (32 uints/row).
static __device__ __forceinline__ void epi_store_fp8(const unsigned short* lds, unsigned* Y, int lb) {
  int tr = threadIdx.x >> 2, q = threadIdx.x & 3;
  int grow = lb * 64 + tr;
  if (grow >= N_NODESC) return;
#pragma unroll
  for (int i = 0; i < 8; ++i) {
    int col = (q + 4 * i) * 4;
    ushort4 v = *(const ushort4*)&lds[tr * 136 + col];
    unsigned pk = pk_fp8x4(bf2f(v.x), bf2f(v.y), bf2f(v.z), bf2f(v.w));
    Y[(size_t)grow * 32 + q + 4 * i] = pk;
  }
}

// ---------------- GEMM layer1 (fp32 in): h(fp8, x16) = (X @ W1) * inv * 16 ----------------
__global__ __launch_bounds__(256) void gemm_l1(const float* __restrict__ xA, const float* __restrict__ xB,
                                               const unsigned short* __restrict__ Wt, const float* __restrict__ inv,
                                               unsigned* __restrict__ H) {
  __shared__ unsigned short lds[64 * 136];
  int side = blockIdx.x / GG, lb = blockIdx.x % GG;
  const float* X = side ? xB : xA;
  const unsigned short* Wm = Wt + (size_t)(side * 2) * 128 * 512;
  const float* iv = inv + side * N_NODESC;
  unsigned* Y = H + (size_t)side * N_NODESC * 32;
  int wave = threadIdx.x >> 6, lane = threadIdx.x & 63;
  int l15 = lane & 15, kb = lane >> 4;
  int row0 = lb * 64 + wave * 16;
  int rA = row0 + l15;
  const bool valid = rA < N_NODESC;
  f32x4 acc[8];
#pragma unroll
  for (int nf = 0; nf < 8; ++nf) acc[nf] = 0.f;
#pragma unroll
  for (int ks = 0; ks < 4; ++ks) {
    int kbase = ks * 32 + kb * 8;
    bf16x8 a;
    if (valid) {
      const float* xp = &X[(size_t)rA * DIMC + kbase];
      float4 x0 = *(const float4*)xp;
      float4 x1 = *(const float4*)(xp + 4);
      a[0] = (short)f2bf(x0.x); a[1] = (short)f2bf(x0.y);
      a[2] = (short)f2bf(x0.z); a[3] = (short)f2bf(x0.w);
      a[4] = (short)f2bf(x1.x); a[5] = (short)f2bf(x1.y);
      a[6] = (short)f2bf(x1.z); a[7] = (short)f2bf(x1.w);
    } else {
      a = (short)0;
    }
    const unsigned short* wp = Wm + (size_t)(ks * 16) * 512 + lane * 8;
#pragma unroll
    for (int nf = 0; nf < 8; ++nf) {
      bf16x8 bh = *(const bf16x8*)(wp + (nf * 2) * 512);
      bf16x8 bl = *(const bf16x8*)(wp + (nf * 2 + 1) * 512);
      acc[nf] = __builtin_amdgcn_mfma_f32_16x16x32_bf16(a, bh, acc[nf], 0, 0, 0);
      acc[nf] = __builtin_amdgcn_mfma_f32_16x16x32_bf16(a, bl, acc[nf], 0, 0, 0);
    }
  }
  int lrow = wave * 16 + kb * 4;
#pragma unroll
  for (int r = 0; r < 4; ++r) {
    int rr = row0 + kb * 4 + r;
    float s = (rr < N_NODESC) ? iv[rr] * 16.0f : 0.f;  // x16 into fp8 range
#pragma unroll
    for (int nf = 0; nf < 8; ++nf) {
      lds[(lrow + r) * 136 + nf * 16 + l15] = f2bf(acc[nf][r] * s);
    }
  }
  __syncthreads();
  epi_store_fp8(lds, Y, lb);
}

// ---------------- GEMM layer2 (bf16 in): h(fp8, x16) = (G @ W2) * inv * 16 ----------------
__global__ __launch_bounds__(256) void gemm_l2(const unsigned short* __restrict__ Gb,
                                               const unsigned short* __restrict__ Wt, const float* __restrict__ inv,
                                               unsigned* __restrict__ H) {
  __shared__ unsigned short lds[64 * 136];
  int side = blockIdx.x / GG, lb = blockIdx.x % GG;
  const unsigned short* X = Gb + (size_t)side * N_NODESC * DIMC;
  const unsigned short* Wm = Wt + (size_t)(side * 2 + 1) * 128 * 512;
  const float* iv = inv + side * N_NODESC;
  unsigned* Y = H + (size_t)side * N_NODESC * 32;
  int wave = threadIdx.x >> 6, lane = threadIdx.x & 63;
  int l15 = lane & 15, kb = lane >> 4;
  int row0 = lb * 64 + wave * 16;
  int rA = row0 + l15;
  const bool valid = rA < N_NODESC;
  f32x4 acc[8];
#pragma unroll
  for (int nf = 0; nf < 8; ++nf) acc[nf] = 0.f;
#pragma unroll
  for (int ks = 0; ks < 4; ++ks) {
    int kbase = ks * 32 + kb * 8;
    bf16x8 a;
    if (valid) {
      a = *(const bf16x8*)&X[(size_t)rA * DIMC + kbase];
    } else {
      a = (short)0;
    }
    const unsigned short* wp = Wm + (size_t)(ks * 16) * 512 + lane * 8;
#pragma unroll
    for (int nf = 0; nf < 8; ++nf) {
      bf16x8 bh = *(const bf16x8*)(wp + (nf * 2) * 512);
      bf16x8 bl = *(const bf16x8*)(wp + (nf * 2 + 1) * 512);
      acc[nf] = __builtin_amdgcn_mfma_f32_16x16x32_bf16(a, bh, acc[nf], 0, 0, 0);
      acc[nf] = __builtin_amdgcn_mfma_f32_16x16x32_bf16(a, bl, acc[nf], 0, 0, 0);
    }
  }
  int lrow = wave * 16 + kb * 4;
#pragma unroll
  for (int r = 0; r < 4; ++r) {
    int rr = row0 + kb * 4 + r;
    float s = (rr < N_NODESC) ? iv[rr] * 16.0f : 0.f;
#pragma unroll
    for (int nf = 0; nf < 8; ++nf) {
      lds[(lrow + r) * 136 + nf * 16 + l15] = f2bf(acc[nf][r] * s);
    }
  }
  __syncthreads();
  epi_store_fp8(lds, Y, lb);
}

// ---------------- aggregation (both sides, fp8 gather, uint2/lane, 16 edges in flight) ----------------
static __device__ __forceinline__ void addu2(float* acc, uint2 u) {
  float4 a = upk_fp8x4(u.x);
  float4 b = upk_fp8x4(u.y);
  acc[0] += a.x; acc[1] += a.y; acc[2] += a.z; acc[3] += a.w;
  acc[4] += b.x; acc[5] += b.y; acc[6] += b.z; acc[7] += b.w;
}

__global__ __launch_bounds__(256) void agg12(const unsigned* __restrict__ H, const float* __restrict__ inv,
                                             const int* __restrict__ rowptr, const unsigned short* __restrict__ csr16,
                                             const float* __restrict__ biasA, const float* __restrict__ biasB,
                                             unsigned short* __restrict__ G, int do_relu) {
  int side = blockIdx.x / AG, lb = blockIdx.x % AG;
  int node = lb * 4 + (threadIdx.x >> 6);
  if (node >= N_NODESC) return;
  const unsigned* Hp = H + (size_t)side * N_NODESC * 32;
  const float* iv = inv + side * N_NODESC;
  const int* rp = rowptr + side * (N_NODESC + 1);
  const unsigned short* csr = csr16 + (size_t)side * N_EDGESC;
  const float* bias = side ? biasB : biasA;
  unsigned short* out = G + (size_t)side * N_NODESC * DIMC;
  int lane = threadIdx.x & 63;
  int g16 = lane & 15;   // 16-lane group: 16 x 8B = 128B row
  int ug2 = g16 * 2;     // uint index base
  int slot = lane >> 4;  // 0..3: 4 edges per load instruction
  int beg = rp[node], end = rp[node + 1];
  float acc[8];
#pragma unroll
  for (int j = 0; j < 8; ++j) acc[j] = 0.f;
  int e = beg;
  for (; e + 16 <= end; e += 16) {  // 16 edges/iter, 4 gathers in flight per lane
    int s0 = csr[e + slot];
    int s1 = csr[e + 4 + slot];
    int s2 = csr[e + 8 + slot];
    int s3 = csr[e + 12 + slot];
    uint2 u0 = *(const uint2*)&Hp[(size_t)s0 * 32 + ug2];
    uint2 u1 = *(const uint2*)&Hp[(size_t)s1 * 32 + ug2];
    uint2 u2 = *(const uint2*)&Hp[(size_t)s2 * 32 + ug2];
    uint2 u3 = *(const uint2*)&Hp[(size_t)s3 * 32 + ug2];
    addu2(acc, u0); addu2(acc, u1); addu2(acc, u2); addu2(acc, u3);
  }
  for (int t2 = e + slot; t2 < end; t2 += 4) {
    uint2 u = *(const uint2*)&Hp[(size_t)csr[t2] * 32 + ug2];
    addu2(acc, u);
  }
#pragma unroll
  for (int j = 0; j < 8; ++j) {
    acc[j] += __shfl_xor(acc[j], 16, 64);
    acc[j] += __shfl_xor(acc[j], 32, 64);
  }
  if (slot == 0) {
    uint2 su = *(const uint2*)&Hp[(size_t)node * 32 + ug2];
    float4 sa = upk_fp8x4(su.x);
    float4 sb = upk_fp8x4(su.y);
    float sc = iv[node] * 0.0625f;  // undo x16
    float4 b0 = *(const float4*)&bias[g16 * 8];
    float4 b1 = *(const float4*)&bias[g16 * 8 + 4];
    float o[8];
    o[0] = (acc[0] + sa.x) * sc + b0.x;
    o[1] = (acc[1] + sa.y) * sc + b0.y;
    o[2] = (acc[2] + sa.z) * sc + b0.z;
    o[3] = (acc[3] + sa.w) * sc + b0.w;
    o[4] = (acc[4] + sb.x) * sc + b1.x;
    o[5] = (acc[5] + sb.y) * sc + b1.y;
    o[6] = (acc[6] + sb.z) * sc + b1.z;
    o[7] = (acc[7] + sb.w) * sc + b1.w;
    if (do_relu) {
#pragma unroll
      for (int j = 0; j < 8; ++j) o[j] = (o[j] > 0.f) ? o[j] : SLOPEF * o[j];
    }
    uint4 w;
    w.x = (unsigned)f2bf(o[0]) | ((unsigned)f2bf(o[1]) << 16);
    w.y = (unsigned)f2bf(o[2]) | ((unsigned)f2bf(o[3]) << 16);
    w.z = (unsigned)f2bf(o[4]) | ((unsigned)f2bf(o[5]) << 16);
    w.w = (unsigned)f2bf(o[6]) | ((unsigned)f2bf(o[7]) << 16);
    *(uint4*)&out[(size_t)node * DIMC + g16 * 8] = w;
  }
}

// ---------------- pooling (both sides, bf16 in) ----------------
__global__ __launch_bounds__(128) void pool2(const unsigned short* __restrict__ G,
                                             const int* __restrict__ batA, const int* __restrict__ batB,
                                             float* __restrict__ psA, float* __restrict__ psB,
                                             int* __restrict__ pcA, int* __restrict__ pcB) {
  int side = blockIdx.x / GG, lb = blockIdx.x % GG;
  const unsigned short* g = G + (size_t)side * N_NODESC * DIMC;
  const int* batch = side ? batB : batA;
  float* psum = side ? psB : psA;
  int* pcnt = side ? pcB : pcA;
  int t = threadIdx.x;
  int n0 = lb * 64;
  int nend = min(n0 + 64, N_NODESC);
  int cur = batch[n0];
  float acc = 0.f;
  int c = 0;
  for (int n = n0; n < nend; ++n) {
    int b = batch[n];
    if (b != cur) {
      atomicAdd(&psum[cur * DIMC + t], acc);
      if (t == 0) atomicAdd(&pcnt[cur], c);
      acc = 0.f;
      c = 0;
      cur = b;
    }
    acc += bf2f(g[(size_t)n * DIMC + t]);
    c += 1;
  }
  atomicAdd(&psum[cur * DIMC + t], acc);
  if (t == 0) atomicAdd(&pcnt[cur], c);
}

// ---------------- fused mean + qkv ----------------
// 384 blocks x 128 thr: task = blk>>6 (0:A@Wq 1:B@Wk 2:B@Wv 3:B@Wq 4:A@Wk 5:A@Wv), r = blk&63.
// Computes mean row inline; tasks 0/3 persist mhA/mhB for later residual/LN use.
__global__ __launch_bounds__(128) void meanqkv(const float* __restrict__ psA, const int* __restrict__ pcA,
                                               const float* __restrict__ psB, const int* __restrict__ pcB,
                                               const float* __restrict__ Wq, const float* __restrict__ bq,
                                               const float* __restrict__ Wk, const float* __restrict__ bk,
                                               const float* __restrict__ Wv, const float* __restrict__ bv,
                                               float* __restrict__ mhA, float* __restrict__ mhB,
                                               float* __restrict__ Q0, float* __restrict__ K0, float* __restrict__ V0,
                                               float* __restrict__ Q1, float* __restrict__ K1, float* __restrict__ V1) {
  __shared__ float xs[DIMC];
  int task = blockIdx.x >> 6, r = blockIdx.x & 63, t = threadIdx.x;
  bool sideA = (task == 0 || task == 4 || task == 5);
  const float* ps = sideA ? psA : psB;
  const int* pc = sideA ? pcA : pcB;
  const float *W, *b;
  float* Y;
  switch (task) {
    case 0: W = Wq; b = bq; Y = Q0; break;
    case 1: W = Wk; b = bk; Y = K0; break;
    case 2: W = Wv; b = bv; Y = V0; break;
    case 3: W = Wq; b = bq; Y = Q1; break;
    case 4: W = Wk; b = bk; Y = K1; break;
    default: W = Wv; b = bv; Y = V1; break;
  }
  float xv = ps[r * DIMC + t] / (float)max(pc[r], 1);
  xs[t] = xv;
  if (task == 0) mhA[r * DIMC + t] = xv;
  if (task == 3) mhB[r * DIMC + t] = xv;
  __syncthreads();
  float acc = b[t];
  for (int k = 0; k < DIMC; ++k) acc += xs[k] * W[k * DIMC + t];
  Y[r * DIMC + t] = acc;
}

__global__ __launch_bounds__(64) void attn_kernel(const float* __restrict__ Q0, const float* __restrict__ K0,
                                                  const float* __restrict__ V0, const float* __restrict__ Q1,
                                                  const float* __restrict__ K1, const float* __restrict__ V1,
                                                  float* __restrict__ O0, float* __restrict__ O1) {
  __shared__ float ps[64];
  int b = blockIdx.x;
  int dir = b >> 8, h = (b >> 6) & 3, q = b & 63;
  const float* Q = dir ? Q1 : Q0;
  const float* K = dir ? K1 : K0;
  const float* V = dir ? V1 : V0;
  float* O = dir ? O1 : O0;
  int k = threadIdx.x;
  const float* qp = Q + q * DIMC + h * HDC;
  const float* kp = K + k * DIMC + h * HDC;
  float s = 0.f;
#pragma unroll
  for (int d = 0; d < HDC; ++d) s += qp[d] * kp[d];
  s *= SCALEF;
  float m = s;
#pragma unroll
  for (int off = 32; off >= 1; off >>= 1) m = fmaxf(m, __shfl_xor(m, off, 64));
  float p = __expf(s - m);
  float sum = p;
#pragma unroll
  for (int off = 32; off >= 1; off >>= 1) sum += __shfl_xor(sum, off, 64);
  p /= sum;
  ps[k] = p;
  __syncthreads();
  int half = k >> 5, d = k & 31;
  float acc = 0.f;
#pragma unroll
  for (int j = 0; j < 32; ++j) {
    int kk = half * 32 + j;
    acc += ps[kk] * V[kk * DIMC + h * HDC + d];
  }
  acc += __shfl_xor(acc, 32, 64);
  if (half == 0) O[q * DIMC + h * HDC + d] = acc;
}

__device__ inline float blk_sum128(float v, float* red) {
#pragma unroll
  for (int off = 32; off >= 1; off >>= 1) v += __shfl_xor(v, off, 64);
  if ((threadIdx.x & 63) == 0) red[threadIdx.x >> 6] = v;
  __syncthreads();
  float r = red[0] + red[1];
  __syncthreads();
  return r;
}

// ---------------- fused oln + ff1 (256 thr: LN on t<128, FF1 on all) ----------------
__global__ __launch_bounds__(256) void olnff1(const float* __restrict__ O0, const float* __restrict__ O1,
                                              const float* __restrict__ mhA, const float* __restrict__ mhB,
                                              const float* __restrict__ Wo, const float* __restrict__ bo,
                                              const float* __restrict__ g1, const float* __restrict__ be1,
                                              const float* __restrict__ Wf1, const float* __restrict__ bf1,
                                              float* __restrict__ X0, float* __restrict__ X1,
                                              float* __restrict__ F0, float* __restrict__ F1) {
  __shared__ float os[DIMC];
  __shared__ float xs[DIMC];
  __shared__ float red4[4];
  int dir = blockIdx.x >> 6, q = blockIdx.x & 63, t = threadIdx.x;
  const float* O = dir ? O1 : O0;
  const float* xq = dir ? mhB : mhA;
  float* Xo = dir ? X1 : X0;
  float* F = dir ? F1 : F0;
  if (t < DIMC) os[t] = O[q * DIMC + t];
  __syncthreads();
  bool act = t < DIMC;
  float acc = 0.f;
  if (act) {
    acc = bo[t] + xq[q * DIMC + t];
    for (int k = 0; k < DIMC; ++k) acc += os[k] * Wo[k * DIMC + t];
  }
  // mean over 128 (waves 2,3 contribute 0)
  float v = act ? acc : 0.f;
#pragma unroll
  for (int off = 32; off >= 1; off >>= 1) v += __shfl_xor(v, off, 64);
  if ((t & 63) == 0) red4[t >> 6] = v;
  __syncthreads();
  float mean = (red4[0] + red4[1] + red4[2] + red4[3]) * (1.f / DIMC);
  __syncthreads();
  float d = act ? (acc - mean) : 0.f;
  float v2 = d * d;
#pragma unroll
  for (int off = 32; off >= 1; off >>= 1) v2 += __shfl_xor(v2, off, 64);
  if ((t & 63) == 0) red4[t >> 6] = v2;
  __syncthreads();
  float var = (red4[0] + red4[1] + red4[2] + red4[3]) * (1.f / DIMC);
  if (act) {
    float xv = d * rsqrtf(var + EPSF) * g1[t] + be1[t];
    xs[t] = xv;
    Xo[q * DIMC + t] = xv;
  }
  __syncthreads();
  float facc = bf1[t];
  for (int k = 0; k < DIMC; ++k) facc += xs[k] * Wf1[k * 256 + t];
  facc = (facc > 0.f) ? facc : SLOPEF * facc;
  F[q * 256 + t] = facc;
}

// ---------------- fused ffln (both dirs) + head ----------------
__global__ __launch_bounds__(128) void fflnhead(const float* __restrict__ F0, const float* __restrict__ F1,
                                                const float* __restrict__ X0, const float* __restrict__ X1,
                                                const float* __restrict__ Wf2, const float* __restrict__ bf2,
                                                const float* __restrict__ g2, const float* __restrict__ be2,
                                                const float* __restrict__ Wl1, const float* __restrict__ bl1,
                                                const float* __restrict__ Wl2, const float* __restrict__ bl2,
                                                float* __restrict__ out) {
  __shared__ float fs[256];
  __shared__ float cs[256];
  __shared__ float red[2];
  int g = blockIdx.x, t = threadIdx.x;
  for (int dir = 0; dir < 2; ++dir) {
    const float* F = dir ? F1 : F0;
    const float* X = dir ? X1 : X0;
    fs[t] = F[g * 256 + t];
    fs[t + 128] = F[g * 256 + t + 128];
    __syncthreads();
    float acc = bf2[t] + X[g * DIMC + t];
    for (int k = 0; k < 256; ++k) acc += fs[k] * Wf2[k * DIMC + t];
    float mean = blk_sum128(acc, red) * (1.f / DIMC);
    float d = acc - mean;
    float var = blk_sum128(d * d, red) * (1.f / DIMC);
    cs[dir * DIMC + t] = d * rsqrtf(var + EPSF) * g2[t] + be2[t];
    __syncthreads();
  }
  float acc = bl1[t];
  for (int k = 0; k < 256; ++k) acc += cs[k] * Wl1[k * DIMC + t];
  acc = fmaxf(acc, 0.f);
  float s = blk_sum128(acc * Wl2[t], red);
  if (t == 0) out[g] = s + bl2[0];
}

// ---------------- host ----------------
extern "C" void kernel_launch(void* const* d_in, const int* in_sizes, int n_in,
                              void* d_out, int out_size, void* d_ws, size_t ws_size,
                              hipStream_t stream) {
  const float* xA = (const float*)d_in[0];
  const float* xB = (const float*)d_in[1];
  const int* eiA = (const int*)d_in[2];
  const int* eiB = (const int*)d_in[3];
  const int* batA = (const int*)d_in[4];
  const int* batB = (const int*)d_in[5];
  const float* WA1 = (const float*)d_in[6];
  const float* WA2 = (const float*)d_in[7];
  const float* WB1 = (const float*)d_in[8];
  const float* WB2 = (const float*)d_in[9];
  const float* Wq = (const float*)d_in[10];
  const float* Wk = (const float*)d_in[11];
  const float* Wv = (const float*)d_in[12];
  const float* Wo = (const float*)d_in[13];
  const float* Wf1 = (const float*)d_in[14];
  const float* Wf2 = (const float*)d_in[15];
  const float* Wl1 = (const float*)d_in[16];
  const float* Wl2 = (const float*)d_in[17];
  const float* bA1 = (const float*)d_in[18];
  const float* bA2 = (const float*)d_in[19];
  const float* bB1 = (const float*)d_in[20];
  const float* bB2 = (const float*)d_in[21];
  const float* bq = (const float*)d_in[22];
  const float* bk = (const float*)d_in[23];
  const float* bv = (const float*)d_in[24];
  const float* bo = (const float*)d_in[25];
  const float* bf1 = (const float*)d_in[26];
  const float* bf2 = (const float*)d_in[27];
  const float* bl1 = (const float*)d_in[28];
  const float* bl2 = (const float*)d_in[29];
  const float* g1 = (const float*)d_in[30];
  const float* be1 = (const float*)d_in[31];
  const float* g2 = (const float*)d_in[32];
  const float* be2 = (const float*)d_in[33];

  char* base = (char*)d_ws;
  size_t off = 0;
  auto alloc = [&](size_t bytes) -> char* {
    char* r = base + off;
    off += (bytes + 255) & ~(size_t)255;
    return r;
  };
  unsigned* h_buf = (unsigned*)alloc((size_t)2 * N_NODESC * 32 * 4);                // fp8 x16, both sides
  unsigned short* g_buf = (unsigned short*)alloc((size_t)2 * N_NODESC * DIMC * 2);  // bf16, both sides
  unsigned* packed = (unsigned*)alloc((size_t)2 * N_EDGESC * 4);
  unsigned short* csr16 = (unsigned short*)alloc((size_t)2 * N_EDGESC * 2);
  int* rowptr = (int*)alloc((size_t)2 * (N_NODESC + 1) * 4);
  float* inv = (float*)alloc((size_t)2 * N_NODESC * 4);
  int* hist = (int*)alloc((size_t)2 * KBLK * NBUK * 4);
  int* bbase = (int*)alloc((size_t)2 * KBLK * NBUK * 4);
  int* bucket_base = (int*)alloc((size_t)2 * (NBUK + 1) * 4);
  unsigned short* wtbuf = (unsigned short*)alloc((size_t)4 * 128 * 512 * 2);
  size_t poff0 = off;
  float* psA = (float*)alloc(NGC * DIMC * 4);
  float* psB = (float*)alloc(NGC * DIMC * 4);
  int* pcA = (int*)alloc(NGC * 4);
  int* pcB = (int*)alloc(NGC * 4);
  size_t pbytes = off - poff0;
  float* mhA = (float*)alloc(NGC * DIMC * 4);
  float* mhB = (float*)alloc(NGC * DIMC * 4);
  float* Q0 = (float*)alloc(NGC * DIMC * 4);
  float* K0 = (float*)alloc(NGC * DIMC * 4);
  float* V0 = (float*)alloc(NGC * DIMC * 4);
  float* Q1 = (float*)alloc(NGC * DIMC * 4);
  float* K1 = (float*)alloc(NGC * DIMC * 4);
  float* V1 = (float*)alloc(NGC * DIMC * 4);
  float* O0 = (float*)alloc(NGC * DIMC * 4);
  float* O1 = (float*)alloc(NGC * DIMC * 4);
  float* X0 = (float*)alloc(NGC * DIMC * 4);
  float* X1 = (float*)alloc(NGC * DIMC * 4);
  float* F0 = (float*)alloc(NGC * 256 * 4);
  float* F1 = (float*)alloc(NGC * 256 * 4);

  hipMemsetAsync(base + poff0, 0, pbytes, stream);
  wconv<<<64, 256, 0, stream>>>(WA1, WA2, WB1, WB2, wtbuf);

  kbhist2<<<2 * KBLK, 1024, 0, stream>>>(eiA, eiB, hist);
  kbscan2<<<2, 1024, 0, stream>>>(hist, bbase, bucket_base);
  kbin2<<<2 * KBLK, 1024, 0, stream>>>(eiA, eiB, bbase, packed);
  kcsr2<<<2 * NBUK, 256, 0, stream>>>(packed, bucket_base, csr16, rowptr, inv);

  gemm_l1<<<2 * GG, 256, 0, stream>>>(xA, xB, wtbuf, inv, h_buf);
  agg12<<<2 * AG, 256, 0, stream>>>(h_buf, inv, rowptr, csr16, bA1, bB1, g_buf, 1);
  gemm_l2<<<2 * GG, 256, 0, stream>>>(g_buf, wtbuf, inv, h_buf);
  agg12<<<2 * AG, 256, 0, stream>>>(h_buf, inv, rowptr, csr16, bA2, bB2, g_buf, 0);
  pool2<<<2 * GG, 128, 0, stream>>>(g_buf, batA, batB, psA, psB, pcA, pcB);

  meanqkv<<<384, 128, 0, stream>>>(psA, pcA, psB, pcB, Wq, bq, Wk, bk, Wv, bv,
                                   mhA, mhB, Q0, K0, V0, Q1, K1, V1);
  attn_kernel<<<512, 64, 0, stream>>>(Q0, K0, V0, Q1, K1, V1, O0, O1);
  olnff1<<<128, 256, 0, stream>>>(O0, O1, mhA, mhB, Wo, bo, g1, be1, Wf1, bf1, X0, X1, F0, F1);
  fflnhead<<<64, 128, 0, stream>>>(F0, F1, X0, X1, Wf2, bf2, g2, be2, Wl1, bl1, Wl2, bl2, (float*)d_out);
}